// Round 3
// baseline (519.230 us; speedup 1.0000x reference)
//
#include <hip/hip_runtime.h>
#include <cstdint>
#include <cstddef>

#define A_LEN  2048
#define D_DIM  512
#define NHEADS 4
#define HDIM   128
#define B_SZ   4
#define ROWS   (B_SZ * A_LEN)   // 8192
#define LN_EPS 1e-5f
#define KSPLIT 4
#define KCHUNK (A_LEN / KSPLIT) // 512

typedef __bf16 bf16x8 __attribute__((ext_vector_type(8)));
typedef __bf16 bf16x4 __attribute__((ext_vector_type(4)));
typedef __bf16 bf16x2 __attribute__((ext_vector_type(2)));
typedef float  f32x4  __attribute__((ext_vector_type(4)));

// ---------------------------------------------------------------------------
// LayerNorm (optional swish before), f32 in, bf16 or f32 out. 1 wave / row.
// ---------------------------------------------------------------------------
__global__ __launch_bounds__(256) void ln_kernel(
    const float* __restrict__ in, void* __restrict__ out,
    const float* __restrict__ w, const float* __restrict__ bvec,
    int do_swish, int out_bf16)
{
    int row  = blockIdx.x * 4 + (threadIdx.x >> 6);
    int lane = threadIdx.x & 63;
    const float* x = in + (size_t)row * D_DIM + lane * 8;
    float4 a  = *(const float4*)x;
    float4 b4 = *(const float4*)(x + 4);
    float v[8] = {a.x, a.y, a.z, a.w, b4.x, b4.y, b4.z, b4.w};
    if (do_swish) {
#pragma unroll
        for (int j = 0; j < 8; ++j) v[j] = v[j] / (1.f + __expf(-v[j]));
    }
    float s = 0.f, s2 = 0.f;
#pragma unroll
    for (int j = 0; j < 8; ++j) { s += v[j]; s2 += v[j] * v[j]; }
#pragma unroll
    for (int off = 32; off; off >>= 1) {
        s  += __shfl_xor(s,  off);
        s2 += __shfl_xor(s2, off);
    }
    float mean = s * (1.f / D_DIM);
    float var  = s2 * (1.f / D_DIM) - mean * mean;
    float inv  = rsqrtf(var + LN_EPS);
    const float* wp = w + lane * 8;
    const float* bp = bvec + lane * 8;
    float r[8];
#pragma unroll
    for (int j = 0; j < 8; ++j) r[j] = (v[j] - mean) * inv * wp[j] + bp[j];
    if (out_bf16) {
        bf16x8 ov;
#pragma unroll
        for (int j = 0; j < 8; ++j) ov[j] = (__bf16)r[j];
        *(bf16x8*)((__bf16*)out + (size_t)row * D_DIM + lane * 8) = ov;
    } else {
        float* o = (float*)out + (size_t)row * D_DIM + lane * 8;
        float4 o0 = {r[0], r[1], r[2], r[3]}, o1 = {r[4], r[5], r[6], r[7]};
        *(float4*)o = o0; *(float4*)(o + 4) = o1;
    }
}

// ---------------------------------------------------------------------------
// f32 -> bf16 copy (weights)
// ---------------------------------------------------------------------------
__global__ __launch_bounds__(256) void conv_w_kernel(
    const float* __restrict__ src, __bf16* __restrict__ dst)
{
    size_t i = ((size_t)blockIdx.x * 256 + threadIdx.x) * 8;
    float4 a = *(const float4*)(src + i);
    float4 b = *(const float4*)(src + i + 4);
    bf16x8 o;
    o[0]=(__bf16)a.x; o[1]=(__bf16)a.y; o[2]=(__bf16)a.z; o[3]=(__bf16)a.w;
    o[4]=(__bf16)b.x; o[5]=(__bf16)b.y; o[6]=(__bf16)b.z; o[7]=(__bf16)b.w;
    *(bf16x8*)(dst + i) = o;
}

// ---------------------------------------------------------------------------
// connectivity int32 (B,1,A,A) -> bitmask uint32 [B][A][A/32]
// ---------------------------------------------------------------------------
__global__ __launch_bounds__(256) void mask_pack_kernel(
    const int* __restrict__ conn, uint32_t* __restrict__ mp)
{
    size_t i = (size_t)blockIdx.x * 256 + threadIdx.x;
    uint64_t bal = __ballot(conn[i] != 0);
    int lane = threadIdx.x & 63;
    size_t w0 = (i & ~(size_t)63) >> 5;
    if (lane == 0)      mp[w0]     = (uint32_t)bal;
    else if (lane == 1) mp[w0 + 1] = (uint32_t)(bal >> 32);
}

// ---------------------------------------------------------------------------
// Vh bf16 [16][2048][128] -> Vt bf16 [16][128][2048]  (per-head transpose)
// ---------------------------------------------------------------------------
__global__ __launch_bounds__(256) void conv_vt_kernel(
    const __bf16* __restrict__ Vh, __bf16* __restrict__ Vt)
{
    __shared__ __bf16 t[HDIM][72];
    int bh = blockIdx.x;
    int a0 = blockIdx.y * 64;
#pragma unroll
    for (int i = 0; i < 4; ++i) {
        int c = threadIdx.x + i * 256;     // 0..1023
        int a_l = c >> 4;                  // 0..63
        int dc  = (c & 15) * 8;            // 0..120
        bf16x8 v = *(const bf16x8*)(Vh + ((size_t)bh * A_LEN + a0 + a_l) * HDIM + dc);
#pragma unroll
        for (int j = 0; j < 8; ++j) t[dc + j][a_l] = v[j];
    }
    __syncthreads();
#pragma unroll
    for (int i = 0; i < 4; ++i) {
        int c = threadIdx.x + i * 256;     // 0..1023
        int d  = c >> 3;                   // 0..127
        int ac = (c & 7) * 8;              // 0..56
        bf16x8 o = *(const bf16x8*)&t[d][ac];
        *(bf16x8*)(Vt + ((size_t)bh * HDIM + d) * A_LEN + a0 + ac) = o;
    }
}

// ---------------------------------------------------------------------------
// bf16 MFMA GEMM: C[M=8192,N=512] = A[M,512]bf16 * W[512,512]^T bf16
// mode 0: f32 out [M][N] (+bias);  mode 1: bf16 out in head layout
//         dst[((b*4+h)*A + a)*128 + d] = C[m][n]*oscale
// ---------------------------------------------------------------------------
__global__ __launch_bounds__(256, 4) void gemm_mfma(
    const __bf16* __restrict__ Am, const __bf16* __restrict__ Wm,
    const float* __restrict__ bias, void* __restrict__ Cout,
    int mode, float oscale)
{
    const int N = D_DIM, K = D_DIM;
    int w = threadIdx.x >> 6, lane = threadIdx.x & 63;
    int grp = lane >> 4, col = lane & 15;
    int m0 = blockIdx.x * 64 + w * 16;
    int n0 = blockIdx.y * 64;
    const __bf16* aptr = Am + (size_t)(m0 + col) * K + grp * 8;
    const __bf16* wptr = Wm + (size_t)(n0 + col) * K + grp * 8;
    f32x4 acc[4] = {{0,0,0,0},{0,0,0,0},{0,0,0,0},{0,0,0,0}};
#pragma unroll 2
    for (int k0 = 0; k0 < K; k0 += 32) {
        bf16x8 af  = *(const bf16x8*)(aptr + k0);
        bf16x8 b0  = *(const bf16x8*)(wptr + k0);
        bf16x8 b1  = *(const bf16x8*)(wptr + (size_t)16 * K + k0);
        bf16x8 b2  = *(const bf16x8*)(wptr + (size_t)32 * K + k0);
        bf16x8 b3  = *(const bf16x8*)(wptr + (size_t)48 * K + k0);
        acc[0] = __builtin_amdgcn_mfma_f32_16x16x32_bf16(af, b0, acc[0], 0, 0, 0);
        acc[1] = __builtin_amdgcn_mfma_f32_16x16x32_bf16(af, b1, acc[1], 0, 0, 0);
        acc[2] = __builtin_amdgcn_mfma_f32_16x16x32_bf16(af, b2, acc[2], 0, 0, 0);
        acc[3] = __builtin_amdgcn_mfma_f32_16x16x32_bf16(af, b3, acc[3], 0, 0, 0);
    }
    if (mode == 0) {
        float* C = (float*)Cout;
#pragma unroll
        for (int nt = 0; nt < 4; ++nt) {
            int n = n0 + nt * 16 + col;
            float bv = bias ? bias[n] : 0.f;
#pragma unroll
            for (int r = 0; r < 4; ++r) {
                int m = m0 + grp * 4 + r;
                C[(size_t)m * N + n] = acc[nt][r] + bv;
            }
        }
    } else {
        __bf16* Cb = (__bf16*)Cout;
#pragma unroll
        for (int nt = 0; nt < 4; ++nt) {
            int n = n0 + nt * 16 + col;
            int h = n >> 7, d = n & 127;
#pragma unroll
            for (int r = 0; r < 4; ++r) {
                int m = m0 + grp * 4 + r;
                int b = m >> 11, a = m & (A_LEN - 1);
                Cb[((size_t)(b * NHEADS + h) * A_LEN + a) * HDIM + d] =
                    (__bf16)(acc[nt][r] * oscale);
            }
        }
    }
}

// ---------------------------------------------------------------------------
// Split-K flash attention. Each block: 64 q rows (4 waves x 16), 512 keys.
// Writes UNNORMALIZED partial O (bf16) + (m,l) stats per row; merge kernel
// combines the KSPLIT splits.
// Qh,Kh: bf16 [16][2048][128] (scale folded into Qh); Vt: bf16 [16][128][2048]
// MP: uint32 [4][2048][64]
// Opart: bf16 [KSPLIT][16][2048][128]; ml: float2 [KSPLIT][16][2048]
// ---------------------------------------------------------------------------
__global__ __launch_bounds__(256, 4) void attn_mfma(
    const __bf16* __restrict__ Qh, const __bf16* __restrict__ Kh,
    const __bf16* __restrict__ Vt, const uint32_t* __restrict__ MP,
    __bf16* __restrict__ Opart, float2* __restrict__ ml)
{
    int bh = blockIdx.y, b = bh >> 2;
    int split = blockIdx.z;
    int ks0 = split * KCHUNK;
    int w = threadIdx.x >> 6, lane = threadIdx.x & 63;
    int qbase = blockIdx.x * 64 + w * 16;
    int grp = lane >> 4, col = lane & 15;

    __shared__ __bf16 Pl[4][16][40];

    const __bf16* qptr = Qh + ((size_t)bh * A_LEN + qbase + col) * HDIM + grp * 8;
    bf16x8 qf[4];
#pragma unroll
    for (int c = 0; c < 4; ++c) qf[c] = *(const bf16x8*)(qptr + c * 32);

    const __bf16* kbase = Kh + ((size_t)bh * A_LEN + ks0 + col) * HDIM + grp * 8;
    const __bf16* vbase = Vt + ((size_t)bh * HDIM + col) * A_LEN + ks0 + grp * 8;
    const uint32_t* mpbase = MP + ((size_t)b * A_LEN + qbase + grp * 4) * (A_LEN / 32)
                               + (ks0 >> 5);

    float m_run[4] = {-1e30f, -1e30f, -1e30f, -1e30f};
    float l_run[4] = {0.f, 0.f, 0.f, 0.f};
    f32x4 oacc[8];
#pragma unroll
    for (int dt = 0; dt < 8; ++dt) oacc[dt] = (f32x4){0,0,0,0};

#pragma unroll 1
    for (int k0 = 0; k0 < KCHUNK; k0 += 32) {
        // K fragments for this tile
        bf16x8 kf[8];
#pragma unroll
        for (int t = 0; t < 2; ++t)
#pragma unroll
            for (int c = 0; c < 4; ++c)
                kf[t * 4 + c] = *(const bf16x8*)(kbase + (size_t)(k0 + t * 16) * HDIM + c * 32);
        // V fragments
        bf16x8 vf[8];
#pragma unroll
        for (int dt = 0; dt < 8; ++dt)
            vf[dt] = *(const bf16x8*)(vbase + (size_t)(dt * 16) * A_LEN + k0);
        // mask words
        uint32_t mw[4];
#pragma unroll
        for (int r = 0; r < 4; ++r) mw[r] = mpbase[(size_t)r * (A_LEN / 32) + (k0 >> 5)];

        // S = Q K^T
        f32x4 s0 = {0,0,0,0}, s1 = {0,0,0,0};
#pragma unroll
        for (int c = 0; c < 4; ++c) {
            s0 = __builtin_amdgcn_mfma_f32_16x16x32_bf16(qf[c], kf[c],     s0, 0, 0, 0);
            s1 = __builtin_amdgcn_mfma_f32_16x16x32_bf16(qf[c], kf[4 + c], s1, 0, 0, 0);
        }

        float sv0[4], sv1[4], tm[4];
#pragma unroll
        for (int r = 0; r < 4; ++r) {
            sv0[r] = ((mw[r] >> col) & 1u)        ? s0[r] : -__builtin_inff();
            sv1[r] = ((mw[r] >> (16 + col)) & 1u) ? s1[r] : -__builtin_inff();
            tm[r] = fmaxf(sv0[r], sv1[r]);
        }
#pragma unroll
        for (int off = 8; off; off >>= 1)
#pragma unroll
            for (int r = 0; r < 4; ++r) tm[r] = fmaxf(tm[r], __shfl_xor(tm[r], off));

        bool need = (tm[0] > m_run[0] + 8.f) | (tm[1] > m_run[1] + 8.f) |
                    (tm[2] > m_run[2] + 8.f) | (tm[3] > m_run[3] + 8.f);
        if (need) {
#pragma unroll
            for (int r = 0; r < 4; ++r) {
                float mn = fmaxf(m_run[r], tm[r]);
                float f  = __expf(m_run[r] - mn);
                m_run[r] = mn;
                l_run[r] *= f;
#pragma unroll
                for (int dt = 0; dt < 8; ++dt) oacc[dt][r] *= f;
            }
        }

        float rs[4];
#pragma unroll
        for (int r = 0; r < 4; ++r) {
            float p0 = __expf(sv0[r] - m_run[r]);
            float p1 = __expf(sv1[r] - m_run[r]);
            rs[r] = p0 + p1;
            Pl[w][grp * 4 + r][col]      = (__bf16)p0;
            Pl[w][grp * 4 + r][16 + col] = (__bf16)p1;
        }
#pragma unroll
        for (int off = 8; off; off >>= 1)
#pragma unroll
            for (int r = 0; r < 4; ++r) rs[r] += __shfl_xor(rs[r], off);
#pragma unroll
        for (int r = 0; r < 4; ++r) l_run[r] += rs[r];

        bf16x8 pa = *(const bf16x8*)&Pl[w][col][grp * 8];

#pragma unroll
        for (int dt = 0; dt < 8; ++dt)
            oacc[dt] = __builtin_amdgcn_mfma_f32_16x16x32_bf16(pa, vf[dt], oacc[dt], 0, 0, 0);
    }

    __bf16* obase = Opart + (((size_t)split * 16 + bh) * A_LEN + qbase + grp * 4) * HDIM + col;
#pragma unroll
    for (int r = 0; r < 4; ++r)
#pragma unroll
        for (int dt = 0; dt < 8; ++dt)
            obase[(size_t)r * HDIM + dt * 16] = (__bf16)oacc[dt][r];

    if (col == 0) {
        float2* mlbase = ml + ((size_t)split * 16 + bh) * A_LEN + qbase + grp * 4;
#pragma unroll
        for (int r = 0; r < 4; ++r) mlbase[r] = make_float2(m_run[r], l_run[r]);
    }
}

// ---------------------------------------------------------------------------
// Merge KSPLIT partial attention results -> Ob f32 [8192][512]
// One wave per (bh, a) row.
// ---------------------------------------------------------------------------
__global__ __launch_bounds__(256) void attn_merge(
    const __bf16* __restrict__ Opart, const float2* __restrict__ ml,
    float* __restrict__ Ob)
{
    int w = threadIdx.x >> 6, lane = threadIdx.x & 63;
    int ridx = blockIdx.x * 4 + w;          // 0..32767
    int bh = ridx >> 11, a = ridx & (A_LEN - 1);
    int b = bh >> 2, h = bh & 3;

    float2 mls[KSPLIT];
    float M = -1e30f;
#pragma unroll
    for (int s = 0; s < KSPLIT; ++s) {
        mls[s] = ml[((size_t)s * 16 + bh) * A_LEN + a];
        M = fmaxf(M, mls[s].x);
    }
    float ws[KSPLIT], wsum = 0.f;
#pragma unroll
    for (int s = 0; s < KSPLIT; ++s) {
        ws[s] = __expf(mls[s].x - M);
        wsum += ws[s] * mls[s].y;
    }
    float inv = 1.f / wsum;

    int d = lane * 2;
    float o0 = 0.f, o1 = 0.f;
#pragma unroll
    for (int s = 0; s < KSPLIT; ++s) {
        bf16x2 v = *(const bf16x2*)(Opart + (((size_t)s * 16 + bh) * A_LEN + a) * HDIM + d);
        o0 += ws[s] * (float)v[0];
        o1 += ws[s] * (float)v[1];
    }
    float2 o = make_float2(o0 * inv, o1 * inv);
    *(float2*)(Ob + ((size_t)b * A_LEN + a) * D_DIM + h * HDIM + d) = o;
}

// ---------------------------------------------------------------------------
extern "C" void kernel_launch(void* const* d_in, const int* in_sizes, int n_in,
                              void* d_out, int out_size, void* d_ws, size_t ws_size,
                              hipStream_t stream)
{
    const float* x      = (const float*)d_in[0];
    const int*   conn   = (const int*)d_in[1];
    const float* Wq     = (const float*)d_in[2];
    const float* Wk     = (const float*)d_in[3];
    const float* Wv     = (const float*)d_in[4];
    const float* norm_w = (const float*)d_in[5];
    const float* norm_b = (const float*)d_in[6];
    const float* ln1_w  = (const float*)d_in[7];
    const float* ln1_b  = (const float*)d_in[8];
    const float* fc1_w  = (const float*)d_in[9];
    const float* fc1_b  = (const float*)d_in[10];
    const float* ln2_w  = (const float*)d_in[11];
    const float* ln2_b  = (const float*)d_in[12];
    const float* fc2_w  = (const float*)d_in[13];
    const float* fc2_b  = (const float*)d_in[14];
    float* out = (float*)d_out;

    char* wsb = (char*)d_ws;
    const size_t WELEM = (size_t)D_DIM * D_DIM;              // 262144
    const size_t MB = (size_t)1 << 20;
    __bf16*   wqb = (__bf16*)(wsb);                          // 5 x 512KB @ 0..2.5MB
    __bf16*   wkb = wqb + WELEM;
    __bf16*   wvb = wkb + WELEM;
    __bf16*   w1b = wvb + WELEM;
    __bf16*   w2b = w1b + WELEM;
    uint32_t* mp  = (uint32_t*)(wsb + 3 * MB);               // 2MB  [3,5)
    float2*   ml  = (float2*)(wsb + 5 * MB);                 // 1MB  [5,6)
    __bf16*   xb  = (__bf16*)(wsb + 6 * MB);                 // 8MB  [6,14)
    __bf16*   Qh  = (__bf16*)(wsb + 14 * MB);                // 8MB  [14,22)
    __bf16*   Kh  = (__bf16*)(wsb + 22 * MB);                // 8MB  [22,30)
    __bf16*   Vh  = (__bf16*)(wsb + 30 * MB);                // 8MB  [30,38)
    __bf16*   Vt  = (__bf16*)(wsb + 38 * MB);                // 8MB  [38,46)
    __bf16*   Op  = (__bf16*)(wsb + 46 * MB);                // 32MB [46,78)
    float*    Ob  = (float*)(wsb + 14 * MB);                 // 16MB [14,30) alias Qh/Kh
    float*    h1  = (float*)(wsb + 30 * MB);                 // 16MB [30,46) alias Vh/Vt
    float*    h2  = (float*)(wsb + 46 * MB);                 // 16MB [46,62) alias Op

    dim3 blk(256);
    dim3 lnGrid(ROWS / 4);
    dim3 gemmGrid(ROWS / 64, D_DIM / 64);
    dim3 attnGrid(A_LEN / 64, B_SZ * NHEADS, KSPLIT);
    dim3 mergeGrid(B_SZ * NHEADS * A_LEN / 4);
    dim3 vtGrid(B_SZ * NHEADS, A_LEN / 64);
    dim3 wGrid(WELEM / 8 / 256);
    dim3 mpGrid((size_t)B_SZ * A_LEN * A_LEN / 256);

    const float QSCALE = 0.08838834764831845f;  // 1/sqrt(128)

    conv_w_kernel<<<wGrid, blk, 0, stream>>>(Wq, wqb);
    conv_w_kernel<<<wGrid, blk, 0, stream>>>(Wk, wkb);
    conv_w_kernel<<<wGrid, blk, 0, stream>>>(Wv, wvb);
    conv_w_kernel<<<wGrid, blk, 0, stream>>>(fc1_w, w1b);
    conv_w_kernel<<<wGrid, blk, 0, stream>>>(fc2_w, w2b);
    mask_pack_kernel<<<mpGrid, blk, 0, stream>>>(conn, mp);

    ln_kernel<<<lnGrid, blk, 0, stream>>>(x, xb, norm_w, norm_b, 0, 1);
    gemm_mfma<<<gemmGrid, blk, 0, stream>>>(xb, wqb, nullptr, Qh, 1, QSCALE);
    gemm_mfma<<<gemmGrid, blk, 0, stream>>>(xb, wkb, nullptr, Kh, 1, 1.0f);
    gemm_mfma<<<gemmGrid, blk, 0, stream>>>(xb, wvb, nullptr, Vh, 1, 1.0f);
    conv_vt_kernel<<<vtGrid, blk, 0, stream>>>(Vh, Vt);
    attn_mfma<<<attnGrid, blk, 0, stream>>>(Qh, Kh, Vt, mp, Op, ml);
    attn_merge<<<mergeGrid, blk, 0, stream>>>(Op, ml, Ob);
    ln_kernel<<<lnGrid, blk, 0, stream>>>(Ob, xb, ln1_w, ln1_b, 1, 1);
    gemm_mfma<<<gemmGrid, blk, 0, stream>>>(xb, w1b, fc1_b, h1, 0, 1.0f);
    ln_kernel<<<lnGrid, blk, 0, stream>>>(h1, xb, ln2_w, ln2_b, 1, 1);
    gemm_mfma<<<gemmGrid, blk, 0, stream>>>(xb, w2b, fc2_b, h2, 0, 1.0f);
    ln_kernel<<<lnGrid, blk, 0, stream>>>(h2, out, norm_w, norm_b, 0, 0);
}

// Round 4
// 366.256 us; speedup vs baseline: 1.4177x; 1.4177x over previous
//
#include <hip/hip_runtime.h>
#include <cstdint>
#include <cstddef>

#define A_LEN  2048
#define D_DIM  512
#define NHEADS 4
#define HDIM   128
#define B_SZ   4
#define ROWS   8192
#define LN_EPS 1e-5f
#define KSPLIT 2
#define KCHUNK (A_LEN / KSPLIT)   // 1024
#define KTILE  32
#define QBLK   128                // 4 waves x 32 q-rows

typedef __bf16 bf16x8 __attribute__((ext_vector_type(8)));
typedef float  f32x4  __attribute__((ext_vector_type(4)));
typedef float  f32x16 __attribute__((ext_vector_type(16)));

static __device__ __forceinline__ uint32_t pkbf(float a, float b) {
    union { __bf16 h[2]; uint32_t u; } t;
    t.h[0] = (__bf16)a; t.h[1] = (__bf16)b;
    return t.u;
}

// ---------------------------------------------------------------------------
// LayerNorm (optional swish), f32 in, bf16 or f32 out. 1 wave / row.
// ---------------------------------------------------------------------------
__global__ __launch_bounds__(256) void ln_kernel(
    const float* __restrict__ in, void* __restrict__ out,
    const float* __restrict__ w, const float* __restrict__ bvec,
    int do_swish, int out_bf16)
{
    int row  = blockIdx.x * 4 + (threadIdx.x >> 6);
    int lane = threadIdx.x & 63;
    const float* x = in + (size_t)row * D_DIM + lane * 8;
    float4 a  = *(const float4*)x;
    float4 b4 = *(const float4*)(x + 4);
    float v[8] = {a.x, a.y, a.z, a.w, b4.x, b4.y, b4.z, b4.w};
    if (do_swish) {
#pragma unroll
        for (int j = 0; j < 8; ++j) v[j] = v[j] / (1.f + __expf(-v[j]));
    }
    float s = 0.f, s2 = 0.f;
#pragma unroll
    for (int j = 0; j < 8; ++j) { s += v[j]; s2 += v[j] * v[j]; }
#pragma unroll
    for (int off = 32; off; off >>= 1) {
        s  += __shfl_xor(s,  off);
        s2 += __shfl_xor(s2, off);
    }
    float mean = s * (1.f / D_DIM);
    float var  = s2 * (1.f / D_DIM) - mean * mean;
    float inv  = rsqrtf(var + LN_EPS);
    const float* wp = w + lane * 8;
    const float* bp = bvec + lane * 8;
    float r[8];
#pragma unroll
    for (int j = 0; j < 8; ++j) r[j] = (v[j] - mean) * inv * wp[j] + bp[j];
    if (out_bf16) {
        bf16x8 ov;
#pragma unroll
        for (int j = 0; j < 8; ++j) ov[j] = (__bf16)r[j];
        *(bf16x8*)((__bf16*)out + (size_t)row * D_DIM + lane * 8) = ov;
    } else {
        float* o = (float*)out + (size_t)row * D_DIM + lane * 8;
        float4 o0 = {r[0], r[1], r[2], r[3]}, o1 = {r[4], r[5], r[6], r[7]};
        *(float4*)o = o0; *(float4*)(o + 4) = o1;
    }
}

// ---------------------------------------------------------------------------
// f32 -> bf16 copy (weights)
// ---------------------------------------------------------------------------
__global__ __launch_bounds__(256) void conv_w_kernel(
    const float* __restrict__ src, __bf16* __restrict__ dst)
{
    size_t i = ((size_t)blockIdx.x * 256 + threadIdx.x) * 8;
    float4 a = *(const float4*)(src + i);
    float4 b = *(const float4*)(src + i + 4);
    bf16x8 o;
    o[0]=(__bf16)a.x; o[1]=(__bf16)a.y; o[2]=(__bf16)a.z; o[3]=(__bf16)a.w;
    o[4]=(__bf16)b.x; o[5]=(__bf16)b.y; o[6]=(__bf16)b.z; o[7]=(__bf16)b.w;
    *(bf16x8*)(dst + i) = o;
}

// ---------------------------------------------------------------------------
// connectivity int32 (B,1,A,A) -> TRANSPOSED bitmask MPT[b][k>>5][q]
// ---------------------------------------------------------------------------
__global__ __launch_bounds__(256) void mask_pack_kernel(
    const int* __restrict__ conn, uint32_t* __restrict__ mpt)
{
    size_t i = (size_t)blockIdx.x * 256 + threadIdx.x;
    uint64_t bal = __ballot(conn[i] != 0);
    int lane = threadIdx.x & 63;
    int b  = (int)(i >> 22);
    int q  = (int)((i >> 11) & (A_LEN - 1));
    int k0 = (int)(i & (A_LEN - 1) & ~(size_t)63);
    if (lane == 0)
        mpt[((size_t)b * 64 + (k0 >> 5)) * A_LEN + q] = (uint32_t)bal;
    else if (lane == 1)
        mpt[((size_t)b * 64 + (k0 >> 5) + 1) * A_LEN + q] = (uint32_t)(bal >> 32);
}

// ---------------------------------------------------------------------------
// Vh bf16 [16][2048][128] -> Vt2 bf16 [16][64][128][32] (tile-major V^T)
// ---------------------------------------------------------------------------
__global__ __launch_bounds__(256) void conv_vt_kernel(
    const __bf16* __restrict__ Vh, __bf16* __restrict__ Vt2)
{
    __shared__ __bf16 t[HDIM][72];
    int bh = blockIdx.x;
    int a0 = blockIdx.y * 64;
#pragma unroll
    for (int i = 0; i < 4; ++i) {
        int c = threadIdx.x + i * 256;     // 0..1023
        int a_l = c >> 4;                  // 0..63
        int dc  = (c & 15) * 8;            // 0..120
        bf16x8 v = *(const bf16x8*)(Vh + ((size_t)bh * A_LEN + a0 + a_l) * HDIM + dc);
#pragma unroll
        for (int j = 0; j < 8; ++j) t[dc + j][a_l] = v[j];
    }
    __syncthreads();
#pragma unroll
    for (int i = 0; i < 4; ++i) {
        int c = threadIdx.x + i * 256;
        int d  = c >> 3;                   // 0..127
        int al = (c & 7) * 8;              // 0..56
        int kt = (a0 >> 5) + (al >> 5);
        int k32 = al & 31;
        bf16x8 o = *(const bf16x8*)&t[d][al];
        *(bf16x8*)(Vt2 + (((size_t)bh * 64 + kt) * HDIM + d) * 32 + k32) = o;
    }
}

// ---------------------------------------------------------------------------
// bf16 MFMA GEMM (unchanged from round 2; 16x16x32 direct-from-global)
// ---------------------------------------------------------------------------
__global__ __launch_bounds__(256, 4) void gemm_mfma(
    const __bf16* __restrict__ Am, const __bf16* __restrict__ Wm,
    const float* __restrict__ bias, void* __restrict__ Cout,
    int mode, float oscale)
{
    const int N = D_DIM, K = D_DIM;
    int w = threadIdx.x >> 6, lane = threadIdx.x & 63;
    int grp = lane >> 4, col = lane & 15;
    int m0 = blockIdx.x * 64 + w * 16;
    int n0 = blockIdx.y * 64;
    const __bf16* aptr = Am + (size_t)(m0 + col) * K + grp * 8;
    const __bf16* wptr = Wm + (size_t)(n0 + col) * K + grp * 8;
    f32x4 acc[4] = {{0,0,0,0},{0,0,0,0},{0,0,0,0},{0,0,0,0}};
#pragma unroll 2
    for (int k0 = 0; k0 < K; k0 += 32) {
        bf16x8 af  = *(const bf16x8*)(aptr + k0);
        bf16x8 b0  = *(const bf16x8*)(wptr + k0);
        bf16x8 b1  = *(const bf16x8*)(wptr + (size_t)16 * K + k0);
        bf16x8 b2  = *(const bf16x8*)(wptr + (size_t)32 * K + k0);
        bf16x8 b3  = *(const bf16x8*)(wptr + (size_t)48 * K + k0);
        acc[0] = __builtin_amdgcn_mfma_f32_16x16x32_bf16(af, b0, acc[0], 0, 0, 0);
        acc[1] = __builtin_amdgcn_mfma_f32_16x16x32_bf16(af, b1, acc[1], 0, 0, 0);
        acc[2] = __builtin_amdgcn_mfma_f32_16x16x32_bf16(af, b2, acc[2], 0, 0, 0);
        acc[3] = __builtin_amdgcn_mfma_f32_16x16x32_bf16(af, b3, acc[3], 0, 0, 0);
    }
    if (mode == 0) {
        float* C = (float*)Cout;
#pragma unroll
        for (int nt = 0; nt < 4; ++nt) {
            int n = n0 + nt * 16 + col;
            float bv = bias ? bias[n] : 0.f;
#pragma unroll
            for (int r = 0; r < 4; ++r) {
                int m = m0 + grp * 4 + r;
                C[(size_t)m * N + n] = acc[nt][r] + bv;
            }
        }
    } else {
        __bf16* Cb = (__bf16*)Cout;
#pragma unroll
        for (int nt = 0; nt < 4; ++nt) {
            int n = n0 + nt * 16 + col;
            int h = n >> 7, d = n & 127;
#pragma unroll
            for (int r = 0; r < 4; ++r) {
                int m = m0 + grp * 4 + r;
                int b = m >> 11, a = m & (A_LEN - 1);
                Cb[((size_t)(b * NHEADS + h) * A_LEN + a) * HDIM + d] =
                    (__bf16)(acc[nt][r] * oscale);
            }
        }
    }
}

// ---------------------------------------------------------------------------
// Flash attention, swapped-QK^T on mfma_32x32x16: lane-local softmax.
// Block: 4 waves x 32 q-rows = 128 q; iterates KCHUNK keys in 32-key tiles.
// K tile reg-staged -> Klds[2][32][144] (288B rows, conflict-free);
// V tile reg-staged from tile-major Vt2 -> Vlds[2][128][40].
// Writes unnormalized f32 partial O + (m,l); merge combines KSPLIT=2.
// ---------------------------------------------------------------------------
__global__ __launch_bounds__(256, 2) void attn_mfma(
    const __bf16* __restrict__ Qh, const __bf16* __restrict__ Kh,
    const __bf16* __restrict__ Vt2, const uint32_t* __restrict__ MPT,
    float* __restrict__ Opart, float2* __restrict__ ml)
{
    int bh = blockIdx.y, b = bh >> 2;
    int split = blockIdx.z;
    int ks0 = split * KCHUNK;
    int tid = threadIdx.x;
    int w = tid >> 6, lane = tid & 63;
    int c31 = lane & 31, hi = lane >> 5;
    int qw = blockIdx.x * QBLK + w * 32;

    __shared__ alignas(16) __bf16 Klds[2][KTILE][144];
    __shared__ alignas(16) __bf16 Vlds[2][HDIM][40];
    __shared__ float Flds[4][32];

    // Q fragments (B operand): col=q=c31, d = s*16 + hi*8 + j
    bf16x8 qf[8];
    {
        const __bf16* qptr = Qh + ((size_t)bh * A_LEN + qw + c31) * HDIM + hi * 8;
#pragma unroll
        for (int s = 0; s < 8; ++s) qf[s] = *(const bf16x8*)(qptr + s * 16);
    }

    const __bf16* Ksrc = Kh + ((size_t)bh * A_LEN + ks0) * HDIM;
    const __bf16* Vsrc = Vt2 + ((size_t)bh * 64 + (ks0 >> 5)) * HDIM * 32;
    const uint32_t* mpq = MPT + ((size_t)b * 64 + (ks0 >> 5)) * A_LEN + qw + c31;

    float m_run = -1e30f, l_part = 0.f;
    f32x16 oacc[4];
#pragma unroll
    for (int dt = 0; dt < 4; ++dt)
#pragma unroll
        for (int j = 0; j < 16; ++j) oacc[dt][j] = 0.f;

    uint4 kr[2], vr[2];
    // prologue: stage tile 0 into buf 0
#pragma unroll
    for (int i = 0; i < 2; ++i) {
        kr[i] = ((const uint4*)Ksrc)[tid + i * 256];
        vr[i] = ((const uint4*)Vsrc)[tid + i * 256];
    }
#pragma unroll
    for (int i = 0; i < 2; ++i) {
        int c = tid + i * 256;
        *(uint4*)&Klds[0][c >> 4][(c & 15) * 8] = kr[i];
        *(uint4*)&Vlds[0][c >> 2][(c & 3) * 8] = vr[i];
    }
    __syncthreads();

    const int nt = KCHUNK / KTILE;   // 32
#pragma unroll 1
    for (int t = 0; t < nt; ++t) {
        int cur = t & 1;
        bool more = (t + 1) < nt;
        if (more) {
#pragma unroll
            for (int i = 0; i < 2; ++i) {
                kr[i] = ((const uint4*)(Ksrc + (size_t)(t + 1) * KTILE * HDIM))[tid + i * 256];
                vr[i] = ((const uint4*)(Vsrc + (size_t)(t + 1) * HDIM * 32))[tid + i * 256];
            }
        }

        uint32_t mw = mpq[(size_t)t * A_LEN];

        // S^T = K Q : S[k=(r&3)+8*(r>>2)+4*hi][q=c31]
        f32x16 St;
#pragma unroll
        for (int j = 0; j < 16; ++j) St[j] = 0.f;
#pragma unroll
        for (int s = 0; s < 8; ++s) {
            bf16x8 kf = *(const bf16x8*)&Klds[cur][c31][s * 16 + hi * 8];
            St = __builtin_amdgcn_mfma_f32_32x32x16_bf16(kf, qf[s], St, 0, 0, 0);
        }

        // mask + in-lane row max
        float sv[16];
        float tmax = -__builtin_inff();
#pragma unroll
        for (int r = 0; r < 16; ++r) {
            int kb = (r & 3) + 8 * (r >> 2) + 4 * hi;
            sv[r] = ((mw >> kb) & 1u) ? St[r] : -__builtin_inff();
            tmax = fmaxf(tmax, sv[r]);
        }
        tmax = fmaxf(tmax, __shfl_xor(tmax, 32));

        // defer-max rescale (THR=8)
        if (__ballot(tmax > m_run + 8.f)) {
            float mnew = fmaxf(m_run, tmax);
            float f = __expf(m_run - mnew);
            m_run = mnew;
            l_part *= f;
            if (lane < 32) Flds[w][c31] = f;
            __asm__ volatile("s_waitcnt lgkmcnt(0)" ::: "memory");
#pragma unroll
            for (int r = 0; r < 16; ++r) {
                float fr = Flds[w][(r & 3) + 8 * (r >> 2) + 4 * hi];
#pragma unroll
                for (int dt = 0; dt < 4; ++dt) oacc[dt][r] *= fr;
            }
        }

        // P = exp(S - m), in-lane partial sum
        float p[16];
#pragma unroll
        for (int r = 0; r < 16; ++r) {
            p[r] = __expf(sv[r] - m_run);
            l_part += p[r];
        }

        // pack P -> bf16, lane-pair exchange -> A-operand fragments
        bf16x8 pa[2];
#pragma unroll
        for (int sub = 0; sub < 2; ++sub) {
            const float* pp = p + sub * 8;
            uint32_t pk01 = pkbf(pp[0], pp[1]);
            uint32_t pk23 = pkbf(pp[2], pp[3]);
            uint32_t pk45 = pkbf(pp[4], pp[5]);
            uint32_t pk67 = pkbf(pp[6], pp[7]);
            uint32_t s1 = hi ? pk01 : pk45;
            uint32_t s2 = hi ? pk23 : pk67;
            uint32_t r1 = __shfl_xor(s1, 32);
            uint32_t r2 = __shfl_xor(s2, 32);
            union { uint32_t u[4]; bf16x8 v; } fu;
            fu.u[0] = hi ? r1 : pk01;
            fu.u[1] = hi ? r2 : pk23;
            fu.u[2] = hi ? pk45 : r1;
            fu.u[3] = hi ? pk67 : r2;
            pa[sub] = fu.v;
        }

        // O += P V  (O: row=q, col=d)
#pragma unroll
        for (int dt = 0; dt < 4; ++dt) {
            bf16x8 v0 = *(const bf16x8*)&Vlds[cur][dt * 32 + c31][hi * 8];
            bf16x8 v1 = *(const bf16x8*)&Vlds[cur][dt * 32 + c31][16 + hi * 8];
            oacc[dt] = __builtin_amdgcn_mfma_f32_32x32x16_bf16(pa[0], v0, oacc[dt], 0, 0, 0);
            oacc[dt] = __builtin_amdgcn_mfma_f32_32x32x16_bf16(pa[1], v1, oacc[dt], 0, 0, 0);
        }

        if (more) {
#pragma unroll
            for (int i = 0; i < 2; ++i) {
                int c = tid + i * 256;
                *(uint4*)&Klds[cur ^ 1][c >> 4][(c & 15) * 8] = kr[i];
                *(uint4*)&Vlds[cur ^ 1][c >> 2][(c & 3) * 8] = vr[i];
            }
        }
        __syncthreads();
    }

    float l_tot = l_part + __shfl_xor(l_part, 32);
    if (lane < 32)
        ml[((size_t)split * 16 + bh) * A_LEN + qw + lane] = make_float2(m_run, l_tot);

    float* ob = Opart + (((size_t)split * 16 + bh) * A_LEN + qw) * HDIM;
#pragma unroll
    for (int r = 0; r < 16; ++r) {
        int ql = (r & 3) + 8 * (r >> 2) + 4 * hi;
#pragma unroll
        for (int dt = 0; dt < 4; ++dt)
            ob[(size_t)ql * HDIM + dt * 32 + c31] = oacc[dt][r];
    }
}

// ---------------------------------------------------------------------------
// Merge KSPLIT=2 partial results -> Ob f32 [8192][512]
// ---------------------------------------------------------------------------
__global__ __launch_bounds__(256) void attn_merge(
    const float* __restrict__ Opart, const float2* __restrict__ ml,
    float* __restrict__ Ob)
{
    int w = threadIdx.x >> 6, lane = threadIdx.x & 63;
    int ridx = blockIdx.x * 4 + w;
    int bh = ridx >> 11, a = ridx & (A_LEN - 1);
    int b = bh >> 2, h = bh & 3;
    float2 ml0 = ml[(size_t)bh * A_LEN + a];
    float2 ml1 = ml[((size_t)16 + bh) * A_LEN + a];
    float M = fmaxf(ml0.x, ml1.x);
    float w0 = __expf(ml0.x - M), w1 = __expf(ml1.x - M);
    float inv = 1.f / (w0 * ml0.y + w1 * ml1.y);
    int d = lane * 2;
    float2 v0 = *(const float2*)(Opart + ((size_t)bh * A_LEN + a) * HDIM + d);
    float2 v1 = *(const float2*)(Opart + (((size_t)16 + bh) * A_LEN + a) * HDIM + d);
    float2 o;
    o.x = (w0 * v0.x + w1 * v1.x) * inv;
    o.y = (w0 * v0.y + w1 * v1.y) * inv;
    *(float2*)(Ob + ((size_t)b * A_LEN + a) * D_DIM + h * HDIM + d) = o;
}

// ---------------------------------------------------------------------------
extern "C" void kernel_launch(void* const* d_in, const int* in_sizes, int n_in,
                              void* d_out, int out_size, void* d_ws, size_t ws_size,
                              hipStream_t stream)
{
    const float* x      = (const float*)d_in[0];
    const int*   conn   = (const int*)d_in[1];
    const float* Wq     = (const float*)d_in[2];
    const float* Wk     = (const float*)d_in[3];
    const float* Wv     = (const float*)d_in[4];
    const float* norm_w = (const float*)d_in[5];
    const float* norm_b = (const float*)d_in[6];
    const float* ln1_w  = (const float*)d_in[7];
    const float* ln1_b  = (const float*)d_in[8];
    const float* fc1_w  = (const float*)d_in[9];
    const float* fc1_b  = (const float*)d_in[10];
    const float* ln2_w  = (const float*)d_in[11];
    const float* ln2_b  = (const float*)d_in[12];
    const float* fc2_w  = (const float*)d_in[13];
    const float* fc2_b  = (const float*)d_in[14];
    float* out = (float*)d_out;

    char* wsb = (char*)d_ws;
    const size_t WELEM = (size_t)D_DIM * D_DIM;
    const size_t MB = (size_t)1 << 20;
    __bf16*   wqb = (__bf16*)(wsb);                          // [0,3) weights
    __bf16*   wkb = wqb + WELEM;
    __bf16*   wvb = wkb + WELEM;
    __bf16*   w1b = wvb + WELEM;
    __bf16*   w2b = w1b + WELEM;
    uint32_t* mpt = (uint32_t*)(wsb + 3 * MB);               // 2MB  [3,5)
    float2*   ml  = (float2*)(wsb + 5 * MB);                 // .5MB [5,6)
    __bf16*   xb  = (__bf16*)(wsb + 6 * MB);                 // 8MB  [6,14)
    __bf16*   Qh  = (__bf16*)(wsb + 14 * MB);                // 8MB  [14,22)
    __bf16*   Kh  = (__bf16*)(wsb + 22 * MB);                // 8MB  [22,30)
    __bf16*   Vh  = (__bf16*)(wsb + 30 * MB);                // 8MB  [30,38)
    __bf16*   Vt2 = (__bf16*)(wsb + 38 * MB);                // 8MB  [38,46)
    float*    Op  = (float*)(wsb + 46 * MB);                 // 32MB [46,78)
    float*    Ob  = (float*)(wsb + 14 * MB);                 // alias Qh/Kh
    float*    h1  = (float*)(wsb + 30 * MB);                 // alias Vh/Vt2
    float*    h2  = (float*)(wsb + 46 * MB);                 // alias Op

    dim3 blk(256);
    dim3 lnGrid(ROWS / 4);
    dim3 gemmGrid(ROWS / 64, D_DIM / 64);
    dim3 attnGrid(A_LEN / QBLK, B_SZ * NHEADS, KSPLIT);
    dim3 mergeGrid(B_SZ * NHEADS * A_LEN / 4);
    dim3 vtGrid(B_SZ * NHEADS, A_LEN / 64);
    dim3 wGrid(WELEM / 8 / 256);
    dim3 mpGrid((size_t)B_SZ * A_LEN * A_LEN / 256);

    const float QSCALE = 0.08838834764831845f;  // 1/sqrt(128)

    conv_w_kernel<<<wGrid, blk, 0, stream>>>(Wq, wqb);
    conv_w_kernel<<<wGrid, blk, 0, stream>>>(Wk, wkb);
    conv_w_kernel<<<wGrid, blk, 0, stream>>>(Wv, wvb);
    conv_w_kernel<<<wGrid, blk, 0, stream>>>(fc1_w, w1b);
    conv_w_kernel<<<wGrid, blk, 0, stream>>>(fc2_w, w2b);
    mask_pack_kernel<<<mpGrid, blk, 0, stream>>>(conn, mpt);

    ln_kernel<<<lnGrid, blk, 0, stream>>>(x, xb, norm_w, norm_b, 0, 1);
    gemm_mfma<<<gemmGrid, blk, 0, stream>>>(xb, wqb, nullptr, Qh, 1, QSCALE);
    gemm_mfma<<<gemmGrid, blk, 0, stream>>>(xb, wkb, nullptr, Kh, 1, 1.0f);
    gemm_mfma<<<gemmGrid, blk, 0, stream>>>(xb, wvb, nullptr, Vh, 1, 1.0f);
    conv_vt_kernel<<<vtGrid, blk, 0, stream>>>(Vh, Vt2);
    attn_mfma<<<attnGrid, blk, 0, stream>>>(Qh, Kh, Vt2, mpt, Op, ml);
    attn_merge<<<mergeGrid, blk, 0, stream>>>(Op, ml, Ob);
    ln_kernel<<<lnGrid, blk, 0, stream>>>(Ob, xb, ln1_w, ln1_b, 1, 1);
    gemm_mfma<<<gemmGrid, blk, 0, stream>>>(xb, w1b, fc1_b, h1, 0, 1.0f);
    ln_kernel<<<lnGrid, blk, 0, stream>>>(h1, xb, ln2_w, ln2_b, 1, 1);
    gemm_mfma<<<gemmGrid, blk, 0, stream>>>(xb, w2b, fc2_b, h2, 0, 1.0f);
    ln_kernel<<<lnGrid, blk, 0, stream>>>(h2, out, norm_w, norm_b, 0, 0);
}

// Round 5
// 353.423 us; speedup vs baseline: 1.4691x; 1.0363x over previous
//
#include <hip/hip_runtime.h>
#include <cstdint>
#include <cstddef>

#define A_LEN  2048
#define D_DIM  512
#define NHEADS 4
#define HDIM   128
#define B_SZ   4
#define ROWS   8192
#define LN_EPS 1e-5f
#define KSPLIT 4
#define KCHUNK (A_LEN / KSPLIT)   // 512
#define KTILE  32
#define QBLK   128                // 4 waves x 32 q-rows

typedef __bf16 bf16x8 __attribute__((ext_vector_type(8)));
typedef __bf16 bf16x2 __attribute__((ext_vector_type(2)));
typedef float  f32x4  __attribute__((ext_vector_type(4)));
typedef float  f32x16 __attribute__((ext_vector_type(16)));

static __device__ __forceinline__ uint32_t pkbf(float a, float b) {
    union { __bf16 h[2]; uint32_t u; } t;
    t.h[0] = (__bf16)a; t.h[1] = (__bf16)b;
    return t.u;
}

// ---------------------------------------------------------------------------
// LayerNorm (optional swish), f32 in, bf16 or f32 out. 1 wave / row.
// ---------------------------------------------------------------------------
__global__ __launch_bounds__(256) void ln_kernel(
    const float* __restrict__ in, void* __restrict__ out,
    const float* __restrict__ w, const float* __restrict__ bvec,
    int do_swish, int out_bf16)
{
    int row  = blockIdx.x * 4 + (threadIdx.x >> 6);
    int lane = threadIdx.x & 63;
    const float* x = in + (size_t)row * D_DIM + lane * 8;
    float4 a  = *(const float4*)x;
    float4 b4 = *(const float4*)(x + 4);
    float v[8] = {a.x, a.y, a.z, a.w, b4.x, b4.y, b4.z, b4.w};
    if (do_swish) {
#pragma unroll
        for (int j = 0; j < 8; ++j) v[j] = v[j] / (1.f + __expf(-v[j]));
    }
    float s = 0.f, s2 = 0.f;
#pragma unroll
    for (int j = 0; j < 8; ++j) { s += v[j]; s2 += v[j] * v[j]; }
#pragma unroll
    for (int off = 32; off; off >>= 1) {
        s  += __shfl_xor(s,  off);
        s2 += __shfl_xor(s2, off);
    }
    float mean = s * (1.f / D_DIM);
    float var  = s2 * (1.f / D_DIM) - mean * mean;
    float inv  = rsqrtf(var + LN_EPS);
    const float* wp = w + lane * 8;
    const float* bp = bvec + lane * 8;
    float r[8];
#pragma unroll
    for (int j = 0; j < 8; ++j) r[j] = (v[j] - mean) * inv * wp[j] + bp[j];
    if (out_bf16) {
        bf16x8 ov;
#pragma unroll
        for (int j = 0; j < 8; ++j) ov[j] = (__bf16)r[j];
        *(bf16x8*)((__bf16*)out + (size_t)row * D_DIM + lane * 8) = ov;
    } else {
        float* o = (float*)out + (size_t)row * D_DIM + lane * 8;
        float4 o0 = {r[0], r[1], r[2], r[3]}, o1 = {r[4], r[5], r[6], r[7]};
        *(float4*)o = o0; *(float4*)(o + 4) = o1;
    }
}

// ---------------------------------------------------------------------------
// f32 -> bf16 copy (weights)
// ---------------------------------------------------------------------------
__global__ __launch_bounds__(256) void conv_w_kernel(
    const float* __restrict__ src, __bf16* __restrict__ dst)
{
    size_t i = ((size_t)blockIdx.x * 256 + threadIdx.x) * 8;
    float4 a = *(const float4*)(src + i);
    float4 b = *(const float4*)(src + i + 4);
    bf16x8 o;
    o[0]=(__bf16)a.x; o[1]=(__bf16)a.y; o[2]=(__bf16)a.z; o[3]=(__bf16)a.w;
    o[4]=(__bf16)b.x; o[5]=(__bf16)b.y; o[6]=(__bf16)b.z; o[7]=(__bf16)b.w;
    *(bf16x8*)(dst + i) = o;
}

// ---------------------------------------------------------------------------
// connectivity int32 (B,1,A,A) -> TRANSPOSED bitmask MPT[b][k>>5][q]
// ---------------------------------------------------------------------------
__global__ __launch_bounds__(256) void mask_pack_kernel(
    const int* __restrict__ conn, uint32_t* __restrict__ mpt)
{
    size_t i = (size_t)blockIdx.x * 256 + threadIdx.x;
    uint64_t bal = __ballot(conn[i] != 0);
    int lane = threadIdx.x & 63;
    int b  = (int)(i >> 22);
    int q  = (int)((i >> 11) & (A_LEN - 1));
    int k0 = (int)(i & (A_LEN - 1) & ~(size_t)63);
    if (lane == 0)
        mpt[((size_t)b * 64 + (k0 >> 5)) * A_LEN + q] = (uint32_t)bal;
    else if (lane == 1)
        mpt[((size_t)b * 64 + (k0 >> 5) + 1) * A_LEN + q] = (uint32_t)(bal >> 32);
}

// ---------------------------------------------------------------------------
// Vh bf16 [16][2048][128] -> Vt2 bf16 [16][64][128][32] (tile-major V^T)
// ---------------------------------------------------------------------------
__global__ __launch_bounds__(256) void conv_vt_kernel(
    const __bf16* __restrict__ Vh, __bf16* __restrict__ Vt2)
{
    __shared__ __bf16 t[HDIM][72];
    int bh = blockIdx.x;
    int a0 = blockIdx.y * 64;
#pragma unroll
    for (int i = 0; i < 4; ++i) {
        int c = threadIdx.x + i * 256;     // 0..1023
        int a_l = c >> 4;                  // 0..63
        int dc  = (c & 15) * 8;            // 0..120
        bf16x8 v = *(const bf16x8*)(Vh + ((size_t)bh * A_LEN + a0 + a_l) * HDIM + dc);
#pragma unroll
        for (int j = 0; j < 8; ++j) t[dc + j][a_l] = v[j];
    }
    __syncthreads();
#pragma unroll
    for (int i = 0; i < 4; ++i) {
        int c = threadIdx.x + i * 256;
        int d  = c >> 3;                   // 0..127
        int al = (c & 7) * 8;              // 0..56
        int kt = (a0 >> 5) + (al >> 5);
        int k32 = al & 31;
        bf16x8 o = *(const bf16x8*)&t[d][al];
        *(bf16x8*)(Vt2 + (((size_t)bh * 64 + kt) * HDIM + d) * 32 + k32) = o;
    }
}

// ---------------------------------------------------------------------------
// LDS-tiled bf16 MFMA GEMM: C[8192,512] = A[8192,512] * W[512,512]^T (+bias)
// 128x128 tile, BK=32, 4 waves (each 64x64 quadrant, 4x4 16x16 tiles),
// reg-staged double-buffered LDS with padded rows (40 bf16 = 80B).
// mode 0: f32 out [M][N] (+bias); mode 1: bf16 out head layout *oscale.
// ---------------------------------------------------------------------------
#define GBM 128
#define GBK 32
#define GPAD 40

__global__ __launch_bounds__(256) void gemm_tile(
    const __bf16* __restrict__ Am, const __bf16* __restrict__ Wm,
    const float* __restrict__ bias, void* __restrict__ Cout,
    int mode, float oscale)
{
    const int N = D_DIM, K = D_DIM;
    __shared__ alignas(16) __bf16 As[2][GBM][GPAD];
    __shared__ alignas(16) __bf16 Ws[2][GBM][GPAD];
    int tid = threadIdx.x;
    int w = tid >> 6, lane = tid & 63;
    int grp = lane >> 4, col = lane & 15;
    int wr = w >> 1, wc = w & 1;              // 64x64 quadrant
    int m0 = blockIdx.x * GBM;
    int n0 = blockIdx.y * GBM;

    int srow = tid >> 1;                      // 0..127
    int skc  = (tid & 1) * 16;                // 0 or 16 (bf16)
    const __bf16* agp = Am + (size_t)(m0 + srow) * K + skc;
    const __bf16* wgp = Wm + (size_t)(n0 + srow) * K + skc;

    uint4 ar0, ar1, wr0, wr1;
    // prologue: stage k0=0 into buf 0
    ar0 = *(const uint4*)agp;       ar1 = *(const uint4*)(agp + 8);
    wr0 = *(const uint4*)wgp;       wr1 = *(const uint4*)(wgp + 8);
    *(uint4*)&As[0][srow][skc] = ar0; *(uint4*)&As[0][srow][skc + 8] = ar1;
    *(uint4*)&Ws[0][srow][skc] = wr0; *(uint4*)&Ws[0][srow][skc + 8] = wr1;
    __syncthreads();

    f32x4 acc[4][4] = {};
#pragma unroll 1
    for (int t = 0; t < K / GBK; ++t) {
        int cur = t & 1;
        bool more = (t + 1) < K / GBK;
        if (more) {
            const __bf16* ap = agp + (size_t)(t + 1) * GBK;
            const __bf16* wp = wgp + (size_t)(t + 1) * GBK;
            ar0 = *(const uint4*)ap; ar1 = *(const uint4*)(ap + 8);
            wr0 = *(const uint4*)wp; wr1 = *(const uint4*)(wp + 8);
        }
        bf16x8 af[4], wf[4];
#pragma unroll
        for (int mt = 0; mt < 4; ++mt)
            af[mt] = *(const bf16x8*)&As[cur][wr * 64 + mt * 16 + col][grp * 8];
#pragma unroll
        for (int nt = 0; nt < 4; ++nt)
            wf[nt] = *(const bf16x8*)&Ws[cur][wc * 64 + nt * 16 + col][grp * 8];
#pragma unroll
        for (int mt = 0; mt < 4; ++mt)
#pragma unroll
            for (int nt = 0; nt < 4; ++nt)
                acc[mt][nt] = __builtin_amdgcn_mfma_f32_16x16x32_bf16(
                    af[mt], wf[nt], acc[mt][nt], 0, 0, 0);
        if (more) {
            int nb = cur ^ 1;
            *(uint4*)&As[nb][srow][skc] = ar0; *(uint4*)&As[nb][srow][skc + 8] = ar1;
            *(uint4*)&Ws[nb][srow][skc] = wr0; *(uint4*)&Ws[nb][srow][skc + 8] = wr1;
        }
        __syncthreads();
    }

    if (mode == 0) {
        float* C = (float*)Cout;
#pragma unroll
        for (int nt = 0; nt < 4; ++nt) {
            int n = n0 + wc * 64 + nt * 16 + col;
            float bv = bias ? bias[n] : 0.f;
#pragma unroll
            for (int mt = 0; mt < 4; ++mt) {
#pragma unroll
                for (int r = 0; r < 4; ++r) {
                    int m = m0 + wr * 64 + mt * 16 + grp * 4 + r;
                    C[(size_t)m * N + n] = acc[mt][nt][r] + bv;
                }
            }
        }
    } else {
        __bf16* Cb = (__bf16*)Cout;
#pragma unroll
        for (int nt = 0; nt < 4; ++nt) {
            int n = n0 + wc * 64 + nt * 16 + col;
            int h = n >> 7, d = n & 127;
#pragma unroll
            for (int mt = 0; mt < 4; ++mt) {
#pragma unroll
                for (int r = 0; r < 4; ++r) {
                    int m = m0 + wr * 64 + mt * 16 + grp * 4 + r;
                    int b = m >> 11, a = m & (A_LEN - 1);
                    Cb[((size_t)(b * NHEADS + h) * A_LEN + a) * HDIM + d] =
                        (__bf16)(acc[mt][nt][r] * oscale);
                }
            }
        }
    }
}

// ---------------------------------------------------------------------------
// Flash attention, swapped-QK^T on mfma_32x32x16: lane-local softmax.
// Block: 4 waves x 32 q-rows; KCHUNK=512 keys in 32-key tiles, KSPLIT=4.
// K tile -> Klds[2][32][128] with chunk-XOR swizzle (chunk ^= row&15);
// V tile -> Vlds[2][128][40] from tile-major Vt2.
// Writes unnormalized bf16 partial O + (m,l); merge combines splits.
// ---------------------------------------------------------------------------
__global__ __launch_bounds__(256, 4) void attn_mfma(
    const __bf16* __restrict__ Qh, const __bf16* __restrict__ Kh,
    const __bf16* __restrict__ Vt2, const uint32_t* __restrict__ MPT,
    __bf16* __restrict__ Opart, float2* __restrict__ ml)
{
    int bh = blockIdx.y, b = bh >> 2;
    int split = blockIdx.z;
    int ks0 = split * KCHUNK;
    int tid = threadIdx.x;
    int w = tid >> 6, lane = tid & 63;
    int c31 = lane & 31, hi = lane >> 5;
    int qw = blockIdx.x * QBLK + w * 32;

    __shared__ alignas(16) __bf16 Klds[2][KTILE][128];
    __shared__ alignas(16) __bf16 Vlds[2][HDIM][40];
    __shared__ float Flds[4][32];

    // Q fragments (B operand): col=q=c31, d = s*16 + hi*8 + j
    bf16x8 qf[8];
    {
        const __bf16* qptr = Qh + ((size_t)bh * A_LEN + qw + c31) * HDIM + hi * 8;
#pragma unroll
        for (int s = 0; s < 8; ++s) qf[s] = *(const bf16x8*)(qptr + s * 16);
    }

    const __bf16* Ksrc = Kh + ((size_t)bh * A_LEN + ks0) * HDIM;
    const __bf16* Vsrc = Vt2 + ((size_t)bh * 64 + (ks0 >> 5)) * HDIM * 32;
    const uint32_t* mpq = MPT + ((size_t)b * 64 + (ks0 >> 5)) * A_LEN + qw + c31;
    int kxor = c31 & 15;

    float m_run = -1e30f, l_part = 0.f;
    f32x16 oacc[4];
#pragma unroll
    for (int dt = 0; dt < 4; ++dt)
#pragma unroll
        for (int j = 0; j < 16; ++j) oacc[dt][j] = 0.f;

    uint4 kr[2], vr[2];
#pragma unroll
    for (int i = 0; i < 2; ++i) {
        kr[i] = ((const uint4*)Ksrc)[tid + i * 256];
        vr[i] = ((const uint4*)Vsrc)[tid + i * 256];
    }
#pragma unroll
    for (int i = 0; i < 2; ++i) {
        int c = tid + i * 256;
        int krow = c >> 4, kch = c & 15;
        *(uint4*)&Klds[0][krow][(kch ^ (krow & 15)) * 8] = kr[i];
        *(uint4*)&Vlds[0][c >> 2][(c & 3) * 8] = vr[i];
    }
    __syncthreads();

    const int nt = KCHUNK / KTILE;   // 16
#pragma unroll 1
    for (int t = 0; t < nt; ++t) {
        int cur = t & 1;
        bool more = (t + 1) < nt;
        if (more) {
#pragma unroll
            for (int i = 0; i < 2; ++i) {
                kr[i] = ((const uint4*)(Ksrc + (size_t)(t + 1) * KTILE * HDIM))[tid + i * 256];
                vr[i] = ((const uint4*)(Vsrc + (size_t)(t + 1) * HDIM * 32))[tid + i * 256];
            }
        }

        uint32_t mw = mpq[(size_t)t * A_LEN];

        // S^T = K Q : S[k=(r&3)+8*(r>>2)+4*hi][q=c31]
        f32x16 St;
#pragma unroll
        for (int j = 0; j < 16; ++j) St[j] = 0.f;
#pragma unroll
        for (int s = 0; s < 8; ++s) {
            bf16x8 kf = *(const bf16x8*)&Klds[cur][c31][(((s << 1) | hi) ^ kxor) * 8];
            St = __builtin_amdgcn_mfma_f32_32x32x16_bf16(kf, qf[s], St, 0, 0, 0);
        }

        // mask + in-lane row max
        float sv[16];
        float tmax = -__builtin_inff();
#pragma unroll
        for (int r = 0; r < 16; ++r) {
            int kb = (r & 3) + 8 * (r >> 2) + 4 * hi;
            sv[r] = ((mw >> kb) & 1u) ? St[r] : -__builtin_inff();
            tmax = fmaxf(tmax, sv[r]);
        }
        tmax = fmaxf(tmax, __shfl_xor(tmax, 32));

        // defer-max rescale (THR=8)
        if (__ballot(tmax > m_run + 8.f)) {
            float mnew = fmaxf(m_run, tmax);
            float f = __expf(m_run - mnew);
            m_run = mnew;
            l_part *= f;
            if (lane < 32) Flds[w][c31] = f;
            __asm__ volatile("s_waitcnt lgkmcnt(0)" ::: "memory");
#pragma unroll
            for (int r = 0; r < 16; ++r) {
                float fr = Flds[w][(r & 3) + 8 * (r >> 2) + 4 * hi];
#pragma unroll
                for (int dt = 0; dt < 4; ++dt) oacc[dt][r] *= fr;
            }
        }

        // P = exp(S - m), in-lane partial sum
        float p[16];
#pragma unroll
        for (int r = 0; r < 16; ++r) {
            p[r] = __expf(sv[r] - m_run);
            l_part += p[r];
        }

        // pack P -> bf16, lane-pair exchange -> A-operand fragments
        bf16x8 pa[2];
#pragma unroll
        for (int sub = 0; sub < 2; ++sub) {
            const float* pp = p + sub * 8;
            uint32_t pk01 = pkbf(pp[0], pp[1]);
            uint32_t pk23 = pkbf(pp[2], pp[3]);
            uint32_t pk45 = pkbf(pp[4], pp[5]);
            uint32_t pk67 = pkbf(pp[6], pp[7]);
            uint32_t s1 = hi ? pk01 : pk45;
            uint32_t s2 = hi ? pk23 : pk67;
            uint32_t r1 = __shfl_xor(s1, 32);
            uint32_t r2 = __shfl_xor(s2, 32);
            union { uint32_t u[4]; bf16x8 v; } fu;
            fu.u[0] = hi ? r1 : pk01;
            fu.u[1] = hi ? r2 : pk23;
            fu.u[2] = hi ? pk45 : r1;
            fu.u[3] = hi ? pk67 : r2;
            pa[sub] = fu.v;
        }

        // O += P V
#pragma unroll
        for (int dt = 0; dt < 4; ++dt) {
            bf16x8 v0 = *(const bf16x8*)&Vlds[cur][dt * 32 + c31][hi * 8];
            bf16x8 v1 = *(const bf16x8*)&Vlds[cur][dt * 32 + c31][16 + hi * 8];
            oacc[dt] = __builtin_amdgcn_mfma_f32_32x32x16_bf16(pa[0], v0, oacc[dt], 0, 0, 0);
            oacc[dt] = __builtin_amdgcn_mfma_f32_32x32x16_bf16(pa[1], v1, oacc[dt], 0, 0, 0);
        }

        if (more) {
#pragma unroll
            for (int i = 0; i < 2; ++i) {
                int c = tid + i * 256;
                int krow = c >> 4, kch = c & 15;
                *(uint4*)&Klds[cur ^ 1][krow][(kch ^ (krow & 15)) * 8] = kr[i];
                *(uint4*)&Vlds[cur ^ 1][c >> 2][(c & 3) * 8] = vr[i];
            }
        }
        __syncthreads();
    }

    float l_tot = l_part + __shfl_xor(l_part, 32);
    if (lane < 32)
        ml[((size_t)split * 16 + bh) * A_LEN + qw + lane] = make_float2(m_run, l_tot);

    __bf16* ob = Opart + (((size_t)split * 16 + bh) * A_LEN + qw) * HDIM;
#pragma unroll
    for (int r = 0; r < 16; ++r) {
        int ql = (r & 3) + 8 * (r >> 2) + 4 * hi;
#pragma unroll
        for (int dt = 0; dt < 4; ++dt)
            ob[(size_t)ql * HDIM + dt * 32 + c31] = (__bf16)oacc[dt][r];
    }
}

// ---------------------------------------------------------------------------
// Merge KSPLIT partial results -> Ob f32 [8192][512]
// ---------------------------------------------------------------------------
__global__ __launch_bounds__(256) void attn_merge(
    const __bf16* __restrict__ Opart, const float2* __restrict__ ml,
    float* __restrict__ Ob)
{
    int w = threadIdx.x >> 6, lane = threadIdx.x & 63;
    int ridx = blockIdx.x * 4 + w;
    int bh = ridx >> 11, a = ridx & (A_LEN - 1);
    int b = bh >> 2, h = bh & 3;

    float2 mls[KSPLIT];
    float M = -1e30f;
#pragma unroll
    for (int s = 0; s < KSPLIT; ++s) {
        mls[s] = ml[((size_t)s * 16 + bh) * A_LEN + a];
        M = fmaxf(M, mls[s].x);
    }
    float wsc[KSPLIT], denom = 0.f;
#pragma unroll
    for (int s = 0; s < KSPLIT; ++s) {
        wsc[s] = __expf(mls[s].x - M);
        denom += wsc[s] * mls[s].y;
    }
    float inv = 1.f / denom;

    int d = lane * 2;
    float o0 = 0.f, o1 = 0.f;
#pragma unroll
    for (int s = 0; s < KSPLIT; ++s) {
        bf16x2 v = *(const bf16x2*)(Opart + (((size_t)s * 16 + bh) * A_LEN + a) * HDIM + d);
        o0 += wsc[s] * (float)v[0];
        o1 += wsc[s] * (float)v[1];
    }
    float2 o = make_float2(o0 * inv, o1 * inv);
    *(float2*)(Ob + ((size_t)b * A_LEN + a) * D_DIM + h * HDIM + d) = o;
}

// ---------------------------------------------------------------------------
extern "C" void kernel_launch(void* const* d_in, const int* in_sizes, int n_in,
                              void* d_out, int out_size, void* d_ws, size_t ws_size,
                              hipStream_t stream)
{
    const float* x      = (const float*)d_in[0];
    const int*   conn   = (const int*)d_in[1];
    const float* Wq     = (const float*)d_in[2];
    const float* Wk     = (const float*)d_in[3];
    const float* Wv     = (const float*)d_in[4];
    const float* norm_w = (const float*)d_in[5];
    const float* norm_b = (const float*)d_in[6];
    const float* ln1_w  = (const float*)d_in[7];
    const float* ln1_b  = (const float*)d_in[8];
    const float* fc1_w  = (const float*)d_in[9];
    const float* fc1_b  = (const float*)d_in[10];
    const float* ln2_w  = (const float*)d_in[11];
    const float* ln2_b  = (const float*)d_in[12];
    const float* fc2_w  = (const float*)d_in[13];
    const float* fc2_b  = (const float*)d_in[14];
    float* out = (float*)d_out;

    char* wsb = (char*)d_ws;
    const size_t WELEM = (size_t)D_DIM * D_DIM;
    const size_t MB = (size_t)1 << 20;
    __bf16*   wqb = (__bf16*)(wsb);                          // [0,3) weights bf16
    __bf16*   wkb = wqb + WELEM;
    __bf16*   wvb = wkb + WELEM;
    __bf16*   w1b = wvb + WELEM;
    __bf16*   w2b = w1b + WELEM;
    uint32_t* mpt = (uint32_t*)(wsb + 3 * MB);               // 2MB  [3,5)
    float2*   ml  = (float2*)(wsb + 5 * MB);                 // 1MB  [5,6)
    __bf16*   xb  = (__bf16*)(wsb + 6 * MB);                 // 8MB  [6,14)
    __bf16*   Qh  = (__bf16*)(wsb + 14 * MB);                // 8MB  [14,22)
    __bf16*   Kh  = (__bf16*)(wsb + 22 * MB);                // 8MB  [22,30)
    __bf16*   Vh  = (__bf16*)(wsb + 30 * MB);                // 8MB  [30,38)
    __bf16*   Vt2 = (__bf16*)(wsb + 38 * MB);                // 8MB  [38,46)
    __bf16*   Op  = (__bf16*)(wsb + 46 * MB);                // 32MB [46,78)
    float*    Ob  = (float*)(wsb + 14 * MB);                 // alias Qh/Kh
    float*    h1  = (float*)(wsb + 30 * MB);                 // alias Vh/Vt2
    float*    h2  = (float*)(wsb + 46 * MB);                 // alias Op

    dim3 blk(256);
    dim3 lnGrid(ROWS / 4);
    dim3 gemmGrid(ROWS / GBM, D_DIM / GBM);                  // (64, 4)
    dim3 attnGrid(A_LEN / QBLK, B_SZ * NHEADS, KSPLIT);
    dim3 mergeGrid(B_SZ * NHEADS * A_LEN / 4);
    dim3 vtGrid(B_SZ * NHEADS, A_LEN / 64);
    dim3 wGrid(WELEM / 8 / 256);
    dim3 mpGrid((size_t)B_SZ * A_LEN * A_LEN / 256);

    const float QSCALE = 0.08838834764831845f;  // 1/sqrt(128)

    conv_w_kernel<<<wGrid, blk, 0, stream>>>(Wq, wqb);
    conv_w_kernel<<<wGrid, blk, 0, stream>>>(Wk, wkb);
    conv_w_kernel<<<wGrid, blk, 0, stream>>>(Wv, wvb);
    conv_w_kernel<<<wGrid, blk, 0, stream>>>(fc1_w, w1b);
    conv_w_kernel<<<wGrid, blk, 0, stream>>>(fc2_w, w2b);
    mask_pack_kernel<<<mpGrid, blk, 0, stream>>>(conn, mpt);

    ln_kernel<<<lnGrid, blk, 0, stream>>>(x, xb, norm_w, norm_b, 0, 1);
    gemm_tile<<<gemmGrid, blk, 0, stream>>>(xb, wqb, nullptr, Qh, 1, QSCALE);
    gemm_tile<<<gemmGrid, blk, 0, stream>>>(xb, wkb, nullptr, Kh, 1, 1.0f);
    gemm_tile<<<gemmGrid, blk, 0, stream>>>(xb, wvb, nullptr, Vh, 1, 1.0f);
    conv_vt_kernel<<<vtGrid, blk, 0, stream>>>(Vh, Vt2);
    attn_mfma<<<attnGrid, blk, 0, stream>>>(Qh, Kh, Vt2, mpt, Op, ml);
    attn_merge<<<mergeGrid, blk, 0, stream>>>(Op, ml, Ob);
    ln_kernel<<<lnGrid, blk, 0, stream>>>(Ob, xb, ln1_w, ln1_b, 1, 1);
    gemm_tile<<<gemmGrid, blk, 0, stream>>>(xb, w1b, fc1_b, h1, 0, 1.0f);
    ln_kernel<<<lnGrid, blk, 0, stream>>>(h1, xb, ln2_w, ln2_b, 1, 1);
    gemm_tile<<<gemmGrid, blk, 0, stream>>>(xb, w2b, fc2_b, h2, 0, 1.0f);
    ln_kernel<<<lnGrid, blk, 0, stream>>>(h2, out, norm_w, norm_b, 0, 0);
}

// Round 6
// 242.045 us; speedup vs baseline: 2.1452x; 1.4602x over previous
//
#include <hip/hip_runtime.h>
#include <cstdint>
#include <cstddef>

#define A_LEN  2048
#define D_DIM  512
#define NHEADS 4
#define HDIM   128
#define B_SZ   4
#define ROWS   8192
#define LN_EPS 1e-5f
#define KSPLIT 4
#define KCHUNK (A_LEN / KSPLIT)   // 512
#define KTILE  32
#define QBLK   128                // 4 waves x 32 q-rows

typedef __bf16 bf16x8 __attribute__((ext_vector_type(8)));
typedef __bf16 bf16x2 __attribute__((ext_vector_type(2)));
typedef float  f32x4  __attribute__((ext_vector_type(4)));
typedef float  f32x16 __attribute__((ext_vector_type(16)));

static __device__ __forceinline__ uint32_t pkbf(float a, float b) {
    union { __bf16 h[2]; uint32_t u; } t;
    t.h[0] = (__bf16)a; t.h[1] = (__bf16)b;
    return t.u;
}

// ---------------------------------------------------------------------------
// LayerNorm (optional swish), f32 in, bf16 or f32 out. 1 wave / row.
// ---------------------------------------------------------------------------
__global__ __launch_bounds__(256) void ln_kernel(
    const float* __restrict__ in, void* __restrict__ out,
    const float* __restrict__ w, const float* __restrict__ bvec,
    int do_swish, int out_bf16)
{
    int row  = blockIdx.x * 4 + (threadIdx.x >> 6);
    int lane = threadIdx.x & 63;
    const float* x = in + (size_t)row * D_DIM + lane * 8;
    float4 a  = *(const float4*)x;
    float4 b4 = *(const float4*)(x + 4);
    float v[8] = {a.x, a.y, a.z, a.w, b4.x, b4.y, b4.z, b4.w};
    if (do_swish) {
#pragma unroll
        for (int j = 0; j < 8; ++j) v[j] = v[j] / (1.f + __expf(-v[j]));
    }
    float s = 0.f, s2 = 0.f;
#pragma unroll
    for (int j = 0; j < 8; ++j) { s += v[j]; s2 += v[j] * v[j]; }
#pragma unroll
    for (int off = 32; off; off >>= 1) {
        s  += __shfl_xor(s,  off);
        s2 += __shfl_xor(s2, off);
    }
    float mean = s * (1.f / D_DIM);
    float var  = s2 * (1.f / D_DIM) - mean * mean;
    float inv  = rsqrtf(var + LN_EPS);
    const float* wp = w + lane * 8;
    const float* bp = bvec + lane * 8;
    float r[8];
#pragma unroll
    for (int j = 0; j < 8; ++j) r[j] = (v[j] - mean) * inv * wp[j] + bp[j];
    if (out_bf16) {
        bf16x8 ov;
#pragma unroll
        for (int j = 0; j < 8; ++j) ov[j] = (__bf16)r[j];
        *(bf16x8*)((__bf16*)out + (size_t)row * D_DIM + lane * 8) = ov;
    } else {
        float* o = (float*)out + (size_t)row * D_DIM + lane * 8;
        float4 o0 = {r[0], r[1], r[2], r[3]}, o1 = {r[4], r[5], r[6], r[7]};
        *(float4*)o = o0; *(float4*)(o + 4) = o1;
    }
}

// ---------------------------------------------------------------------------
// f32 -> bf16 copy (weights)
// ---------------------------------------------------------------------------
__global__ __launch_bounds__(256) void conv_w_kernel(
    const float* __restrict__ src, __bf16* __restrict__ dst)
{
    size_t i = ((size_t)blockIdx.x * 256 + threadIdx.x) * 8;
    float4 a = *(const float4*)(src + i);
    float4 b = *(const float4*)(src + i + 4);
    bf16x8 o;
    o[0]=(__bf16)a.x; o[1]=(__bf16)a.y; o[2]=(__bf16)a.z; o[3]=(__bf16)a.w;
    o[4]=(__bf16)b.x; o[5]=(__bf16)b.y; o[6]=(__bf16)b.z; o[7]=(__bf16)b.w;
    *(bf16x8*)(dst + i) = o;
}

// ---------------------------------------------------------------------------
// connectivity int32 (B,1,A,A) -> TRANSPOSED bitmask MPT[b][k>>5][q]
// ---------------------------------------------------------------------------
__global__ __launch_bounds__(256) void mask_pack_kernel(
    const int* __restrict__ conn, uint32_t* __restrict__ mpt)
{
    size_t i = (size_t)blockIdx.x * 256 + threadIdx.x;
    uint64_t bal = __ballot(conn[i] != 0);
    int lane = threadIdx.x & 63;
    int b  = (int)(i >> 22);
    int q  = (int)((i >> 11) & (A_LEN - 1));
    int k0 = (int)(i & (A_LEN - 1) & ~(size_t)63);
    if (lane == 0)
        mpt[((size_t)b * 64 + (k0 >> 5)) * A_LEN + q] = (uint32_t)bal;
    else if (lane == 1)
        mpt[((size_t)b * 64 + (k0 >> 5) + 1) * A_LEN + q] = (uint32_t)(bal >> 32);
}

// ---------------------------------------------------------------------------
// Vh bf16 [16][2048][128] -> Vt2 bf16 [16][64][128][32] (tile-major V^T)
// ---------------------------------------------------------------------------
__global__ __launch_bounds__(256) void conv_vt_kernel(
    const __bf16* __restrict__ Vh, __bf16* __restrict__ Vt2)
{
    __shared__ __bf16 t[HDIM][72];
    int bh = blockIdx.x;
    int a0 = blockIdx.y * 64;
#pragma unroll
    for (int i = 0; i < 4; ++i) {
        int c = threadIdx.x + i * 256;     // 0..1023
        int a_l = c >> 4;                  // 0..63
        int dc  = (c & 15) * 8;            // 0..120
        bf16x8 v = *(const bf16x8*)(Vh + ((size_t)bh * A_LEN + a0 + a_l) * HDIM + dc);
#pragma unroll
        for (int j = 0; j < 8; ++j) t[dc + j][a_l] = v[j];
    }
    __syncthreads();
#pragma unroll
    for (int i = 0; i < 4; ++i) {
        int c = threadIdx.x + i * 256;
        int d  = c >> 3;                   // 0..127
        int al = (c & 7) * 8;              // 0..56
        int kt = (a0 >> 5) + (al >> 5);
        int k32 = al & 31;
        bf16x8 o = *(const bf16x8*)&t[d][al];
        *(bf16x8*)(Vt2 + (((size_t)bh * 64 + kt) * HDIM + d) * 32 + k32) = o;
    }
}

// ---------------------------------------------------------------------------
// LDS-tiled bf16 MFMA GEMM: C[8192,512] = A[8192,512] * W[512,512]^T (+bias)
// 128x128 tile, BK=32, 4 waves, reg-staged double-buffered LDS.
// ---------------------------------------------------------------------------
#define GBM 128
#define GBK 32
#define GPAD 40

__global__ __launch_bounds__(256) void gemm_tile(
    const __bf16* __restrict__ Am, const __bf16* __restrict__ Wm,
    const float* __restrict__ bias, void* __restrict__ Cout,
    int mode, float oscale)
{
    const int N = D_DIM, K = D_DIM;
    __shared__ alignas(16) __bf16 As[2][GBM][GPAD];
    __shared__ alignas(16) __bf16 Ws[2][GBM][GPAD];
    int tid = threadIdx.x;
    int w = tid >> 6, lane = tid & 63;
    int grp = lane >> 4, col = lane & 15;
    int wr = w >> 1, wc = w & 1;              // 64x64 quadrant
    int m0 = blockIdx.x * GBM;
    int n0 = blockIdx.y * GBM;

    int srow = tid >> 1;                      // 0..127
    int skc  = (tid & 1) * 16;                // 0 or 16 (bf16)
    const __bf16* agp = Am + (size_t)(m0 + srow) * K + skc;
    const __bf16* wgp = Wm + (size_t)(n0 + srow) * K + skc;

    uint4 ar0, ar1, wr0, wr1;
    ar0 = *(const uint4*)agp;       ar1 = *(const uint4*)(agp + 8);
    wr0 = *(const uint4*)wgp;       wr1 = *(const uint4*)(wgp + 8);
    *(uint4*)&As[0][srow][skc] = ar0; *(uint4*)&As[0][srow][skc + 8] = ar1;
    *(uint4*)&Ws[0][srow][skc] = wr0; *(uint4*)&Ws[0][srow][skc + 8] = wr1;
    __syncthreads();

    f32x4 acc[4][4] = {};
#pragma unroll 1
    for (int t = 0; t < K / GBK; ++t) {
        int cur = t & 1;
        bool more = (t + 1) < K / GBK;
        if (more) {
            const __bf16* ap = agp + (size_t)(t + 1) * GBK;
            const __bf16* wp = wgp + (size_t)(t + 1) * GBK;
            ar0 = *(const uint4*)ap; ar1 = *(const uint4*)(ap + 8);
            wr0 = *(const uint4*)wp; wr1 = *(const uint4*)(wp + 8);
        }
        bf16x8 af[4], wf[4];
#pragma unroll
        for (int mt = 0; mt < 4; ++mt)
            af[mt] = *(const bf16x8*)&As[cur][wr * 64 + mt * 16 + col][grp * 8];
#pragma unroll
        for (int nt = 0; nt < 4; ++nt)
            wf[nt] = *(const bf16x8*)&Ws[cur][wc * 64 + nt * 16 + col][grp * 8];
        __builtin_amdgcn_s_setprio(1);
#pragma unroll
        for (int mt = 0; mt < 4; ++mt)
#pragma unroll
            for (int nt = 0; nt < 4; ++nt)
                acc[mt][nt] = __builtin_amdgcn_mfma_f32_16x16x32_bf16(
                    af[mt], wf[nt], acc[mt][nt], 0, 0, 0);
        __builtin_amdgcn_s_setprio(0);
        if (more) {
            int nb = cur ^ 1;
            *(uint4*)&As[nb][srow][skc] = ar0; *(uint4*)&As[nb][srow][skc + 8] = ar1;
            *(uint4*)&Ws[nb][srow][skc] = wr0; *(uint4*)&Ws[nb][srow][skc + 8] = wr1;
        }
        __syncthreads();
    }

    if (mode == 0) {
        float* C = (float*)Cout;
#pragma unroll
        for (int nt = 0; nt < 4; ++nt) {
            int n = n0 + wc * 64 + nt * 16 + col;
            float bv = bias ? bias[n] : 0.f;
#pragma unroll
            for (int mt = 0; mt < 4; ++mt) {
#pragma unroll
                for (int r = 0; r < 4; ++r) {
                    int m = m0 + wr * 64 + mt * 16 + grp * 4 + r;
                    C[(size_t)m * N + n] = acc[mt][nt][r] + bv;
                }
            }
        }
    } else {
        __bf16* Cb = (__bf16*)Cout;
#pragma unroll
        for (int nt = 0; nt < 4; ++nt) {
            int n = n0 + wc * 64 + nt * 16 + col;
            int h = n >> 7, d = n & 127;
#pragma unroll
            for (int mt = 0; mt < 4; ++mt) {
#pragma unroll
                for (int r = 0; r < 4; ++r) {
                    int m = m0 + wr * 64 + mt * 16 + grp * 4 + r;
                    int b = m >> 11, a = m & (A_LEN - 1);
                    Cb[((size_t)(b * NHEADS + h) * A_LEN + a) * HDIM + d] =
                        (__bf16)(acc[mt][nt][r] * oscale);
                }
            }
        }
    }
}

// ---------------------------------------------------------------------------
// Flash attention, swapped-QK^T on mfma_32x32x16: lane-local softmax.
// Block: 4 waves x 32 q-rows; KCHUNK=512 keys in 32-key tiles, KSPLIT=4.
// K tile -> Klds[2][32][128] chunk-XOR swizzled; V tile -> Vlds[2][128][40].
// launch_bounds (256,2): ~190 VGPRs needed -- (256,4) spilled ~1GB (round 5).
// ---------------------------------------------------------------------------
__global__ __launch_bounds__(256, 2) void attn_mfma(
    const __bf16* __restrict__ Qh, const __bf16* __restrict__ Kh,
    const __bf16* __restrict__ Vt2, const uint32_t* __restrict__ MPT,
    __bf16* __restrict__ Opart, float2* __restrict__ ml)
{
    int bh = blockIdx.y, b = bh >> 2;
    int split = blockIdx.z;
    int ks0 = split * KCHUNK;
    int tid = threadIdx.x;
    int w = tid >> 6, lane = tid & 63;
    int c31 = lane & 31, hi = lane >> 5;
    int qw = blockIdx.x * QBLK + w * 32;

    __shared__ alignas(16) __bf16 Klds[2][KTILE][128];
    __shared__ alignas(16) __bf16 Vlds[2][HDIM][40];
    __shared__ float Flds[4][32];

    // Q fragments (B operand): col=q=c31, d = s*16 + hi*8 + j
    bf16x8 qf[8];
    {
        const __bf16* qptr = Qh + ((size_t)bh * A_LEN + qw + c31) * HDIM + hi * 8;
#pragma unroll
        for (int s = 0; s < 8; ++s) qf[s] = *(const bf16x8*)(qptr + s * 16);
    }

    const __bf16* Ksrc = Kh + ((size_t)bh * A_LEN + ks0) * HDIM;
    const __bf16* Vsrc = Vt2 + ((size_t)bh * 64 + (ks0 >> 5)) * HDIM * 32;
    const uint32_t* mpq = MPT + ((size_t)b * 64 + (ks0 >> 5)) * A_LEN + qw + c31;
    int kxor = c31 & 15;

    float m_run = -1e30f, l_part = 0.f;
    f32x16 oacc[4];
#pragma unroll
    for (int dt = 0; dt < 4; ++dt)
#pragma unroll
        for (int j = 0; j < 16; ++j) oacc[dt][j] = 0.f;

    uint4 kr[2], vr[2];
#pragma unroll
    for (int i = 0; i < 2; ++i) {
        kr[i] = ((const uint4*)Ksrc)[tid + i * 256];
        vr[i] = ((const uint4*)Vsrc)[tid + i * 256];
    }
#pragma unroll
    for (int i = 0; i < 2; ++i) {
        int c = tid + i * 256;
        int krow = c >> 4, kch = c & 15;
        *(uint4*)&Klds[0][krow][(kch ^ (krow & 15)) * 8] = kr[i];
        *(uint4*)&Vlds[0][c >> 2][(c & 3) * 8] = vr[i];
    }
    __syncthreads();

    const int nt = KCHUNK / KTILE;   // 16
#pragma unroll 1
    for (int t = 0; t < nt; ++t) {
        int cur = t & 1;
        bool more = (t + 1) < nt;
        if (more) {
#pragma unroll
            for (int i = 0; i < 2; ++i) {
                kr[i] = ((const uint4*)(Ksrc + (size_t)(t + 1) * KTILE * HDIM))[tid + i * 256];
                vr[i] = ((const uint4*)(Vsrc + (size_t)(t + 1) * HDIM * 32))[tid + i * 256];
            }
        }

        uint32_t mw = mpq[(size_t)t * A_LEN];

        // S^T = K Q : S[k=(r&3)+8*(r>>2)+4*hi][q=c31]
        f32x16 St;
#pragma unroll
        for (int j = 0; j < 16; ++j) St[j] = 0.f;
        __builtin_amdgcn_s_setprio(1);
#pragma unroll
        for (int s = 0; s < 8; ++s) {
            bf16x8 kf = *(const bf16x8*)&Klds[cur][c31][(((s << 1) | hi) ^ kxor) * 8];
            St = __builtin_amdgcn_mfma_f32_32x32x16_bf16(kf, qf[s], St, 0, 0, 0);
        }
        __builtin_amdgcn_s_setprio(0);

        // mask in place + in-lane row max
        float tmax = -__builtin_inff();
#pragma unroll
        for (int r = 0; r < 16; ++r) {
            int kb = (r & 3) + 8 * (r >> 2) + 4 * hi;
            St[r] = ((mw >> kb) & 1u) ? St[r] : -__builtin_inff();
            tmax = fmaxf(tmax, St[r]);
        }
        tmax = fmaxf(tmax, __shfl_xor(tmax, 32));

        // defer-max rescale (THR=8)
        if (__ballot(tmax > m_run + 8.f)) {
            float mnew = fmaxf(m_run, tmax);
            float f = __expf(m_run - mnew);
            m_run = mnew;
            l_part *= f;
            if (lane < 32) Flds[w][c31] = f;
            __asm__ volatile("s_waitcnt lgkmcnt(0)" ::: "memory");
#pragma unroll
            for (int r = 0; r < 16; ++r) {
                float fr = Flds[w][(r & 3) + 8 * (r >> 2) + 4 * hi];
#pragma unroll
                for (int dt = 0; dt < 4; ++dt) oacc[dt][r] *= fr;
            }
        }

        // P = exp(S - m), in-lane partial sum
        float p[16];
#pragma unroll
        for (int r = 0; r < 16; ++r) {
            p[r] = __expf(St[r] - m_run);
            l_part += p[r];
        }

        // pack P -> bf16, lane-pair exchange -> A-operand fragments
        bf16x8 pa[2];
#pragma unroll
        for (int sub = 0; sub < 2; ++sub) {
            const float* pp = p + sub * 8;
            uint32_t pk01 = pkbf(pp[0], pp[1]);
            uint32_t pk23 = pkbf(pp[2], pp[3]);
            uint32_t pk45 = pkbf(pp[4], pp[5]);
            uint32_t pk67 = pkbf(pp[6], pp[7]);
            uint32_t s1 = hi ? pk01 : pk45;
            uint32_t s2 = hi ? pk23 : pk67;
            uint32_t r1 = __shfl_xor(s1, 32);
            uint32_t r2 = __shfl_xor(s2, 32);
            union { uint32_t u[4]; bf16x8 v; } fu;
            fu.u[0] = hi ? r1 : pk01;
            fu.u[1] = hi ? r2 : pk23;
            fu.u[2] = hi ? pk45 : r1;
            fu.u[3] = hi ? pk67 : r2;
            pa[sub] = fu.v;
        }

        // O += P V
        __builtin_amdgcn_s_setprio(1);
#pragma unroll
        for (int dt = 0; dt < 4; ++dt) {
            bf16x8 v0 = *(const bf16x8*)&Vlds[cur][dt * 32 + c31][hi * 8];
            bf16x8 v1 = *(const bf16x8*)&Vlds[cur][dt * 32 + c31][16 + hi * 8];
            oacc[dt] = __builtin_amdgcn_mfma_f32_32x32x16_bf16(pa[0], v0, oacc[dt], 0, 0, 0);
            oacc[dt] = __builtin_amdgcn_mfma_f32_32x32x16_bf16(pa[1], v1, oacc[dt], 0, 0, 0);
        }
        __builtin_amdgcn_s_setprio(0);

        if (more) {
#pragma unroll
            for (int i = 0; i < 2; ++i) {
                int c = tid + i * 256;
                int krow = c >> 4, kch = c & 15;
                *(uint4*)&Klds[cur ^ 1][krow][(kch ^ (krow & 15)) * 8] = kr[i];
                *(uint4*)&Vlds[cur ^ 1][c >> 2][(c & 3) * 8] = vr[i];
            }
        }
        __syncthreads();
    }

    float l_tot = l_part + __shfl_xor(l_part, 32);
    if (lane < 32)
        ml[((size_t)split * 16 + bh) * A_LEN + qw + lane] = make_float2(m_run, l_tot);

    __bf16* ob = Opart + (((size_t)split * 16 + bh) * A_LEN + qw) * HDIM;
#pragma unroll
    for (int r = 0; r < 16; ++r) {
        int ql = (r & 3) + 8 * (r >> 2) + 4 * hi;
#pragma unroll
        for (int dt = 0; dt < 4; ++dt)
            ob[(size_t)ql * HDIM + dt * 32 + c31] = (__bf16)oacc[dt][r];
    }
}

// ---------------------------------------------------------------------------
// Merge KSPLIT partial results -> Ob f32 [8192][512]
// ---------------------------------------------------------------------------
__global__ __launch_bounds__(256) void attn_merge(
    const __bf16* __restrict__ Opart, const float2* __restrict__ ml,
    float* __restrict__ Ob)
{
    int w = threadIdx.x >> 6, lane = threadIdx.x & 63;
    int ridx = blockIdx.x * 4 + w;
    int bh = ridx >> 11, a = ridx & (A_LEN - 1);
    int b = bh >> 2, h = bh & 3;

    float2 mls[KSPLIT];
    float M = -1e30f;
#pragma unroll
    for (int s = 0; s < KSPLIT; ++s) {
        mls[s] = ml[((size_t)s * 16 + bh) * A_LEN + a];
        M = fmaxf(M, mls[s].x);
    }
    float wsc[KSPLIT], denom = 0.f;
#pragma unroll
    for (int s = 0; s < KSPLIT; ++s) {
        wsc[s] = __expf(mls[s].x - M);
        denom += wsc[s] * mls[s].y;
    }
    float inv = 1.f / denom;

    int d = lane * 2;
    float o0 = 0.f, o1 = 0.f;
#pragma unroll
    for (int s = 0; s < KSPLIT; ++s) {
        bf16x2 v = *(const bf16x2*)(Opart + (((size_t)s * 16 + bh) * A_LEN + a) * HDIM + d);
        o0 += wsc[s] * (float)v[0];
        o1 += wsc[s] * (float)v[1];
    }
    float2 o = make_float2(o0 * inv, o1 * inv);
    *(float2*)(Ob + ((size_t)b * A_LEN + a) * D_DIM + h * HDIM + d) = o;
}

// ---------------------------------------------------------------------------
extern "C" void kernel_launch(void* const* d_in, const int* in_sizes, int n_in,
                              void* d_out, int out_size, void* d_ws, size_t ws_size,
                              hipStream_t stream)
{
    const float* x      = (const float*)d_in[0];
    const int*   conn   = (const int*)d_in[1];
    const float* Wq     = (const float*)d_in[2];
    const float* Wk     = (const float*)d_in[3];
    const float* Wv     = (const float*)d_in[4];
    const float* norm_w = (const float*)d_in[5];
    const float* norm_b = (const float*)d_in[6];
    const float* ln1_w  = (const float*)d_in[7];
    const float* ln1_b  = (const float*)d_in[8];
    const float* fc1_w  = (const float*)d_in[9];
    const float* fc1_b  = (const float*)d_in[10];
    const float* ln2_w  = (const float*)d_in[11];
    const float* ln2_b  = (const float*)d_in[12];
    const float* fc2_w  = (const float*)d_in[13];
    const float* fc2_b  = (const float*)d_in[14];
    float* out = (float*)d_out;

    char* wsb = (char*)d_ws;
    const size_t WELEM = (size_t)D_DIM * D_DIM;
    const size_t MB = (size_t)1 << 20;
    __bf16*   wqb = (__bf16*)(wsb);                          // [0,3) weights bf16
    __bf16*   wkb = wqb + WELEM;
    __bf16*   wvb = wkb + WELEM;
    __bf16*   w1b = wvb + WELEM;
    __bf16*   w2b = w1b + WELEM;
    uint32_t* mpt = (uint32_t*)(wsb + 3 * MB);               // 2MB  [3,5)
    float2*   ml  = (float2*)(wsb + 5 * MB);                 // 1MB  [5,6)
    __bf16*   xb  = (__bf16*)(wsb + 6 * MB);                 // 8MB  [6,14)
    __bf16*   Qh  = (__bf16*)(wsb + 14 * MB);                // 8MB  [14,22)
    __bf16*   Kh  = (__bf16*)(wsb + 22 * MB);                // 8MB  [22,30)
    __bf16*   Vh  = (__bf16*)(wsb + 30 * MB);                // 8MB  [30,38)
    __bf16*   Vt2 = (__bf16*)(wsb + 38 * MB);                // 8MB  [38,46)
    __bf16*   Op  = (__bf16*)(wsb + 46 * MB);                // 32MB [46,78)
    float*    Ob  = (float*)(wsb + 14 * MB);                 // alias Qh/Kh
    float*    h1  = (float*)(wsb + 30 * MB);                 // alias Vh/Vt2
    float*    h2  = (float*)(wsb + 46 * MB);                 // alias Op

    dim3 blk(256);
    dim3 lnGrid(ROWS / 4);
    dim3 gemmGrid(ROWS / GBM, D_DIM / GBM);                  // (64, 4)
    dim3 attnGrid(A_LEN / QBLK, B_SZ * NHEADS, KSPLIT);
    dim3 mergeGrid(B_SZ * NHEADS * A_LEN / 4);
    dim3 vtGrid(B_SZ * NHEADS, A_LEN / 64);
    dim3 wGrid(WELEM / 8 / 256);
    dim3 mpGrid((size_t)B_SZ * A_LEN * A_LEN / 256);

    const float QSCALE = 0.08838834764831845f;  // 1/sqrt(128)

    conv_w_kernel<<<wGrid, blk, 0, stream>>>(Wq, wqb);
    conv_w_kernel<<<wGrid, blk, 0, stream>>>(Wk, wkb);
    conv_w_kernel<<<wGrid, blk, 0, stream>>>(Wv, wvb);
    conv_w_kernel<<<wGrid, blk, 0, stream>>>(fc1_w, w1b);
    conv_w_kernel<<<wGrid, blk, 0, stream>>>(fc2_w, w2b);
    mask_pack_kernel<<<mpGrid, blk, 0, stream>>>(conn, mpt);

    ln_kernel<<<lnGrid, blk, 0, stream>>>(x, xb, norm_w, norm_b, 0, 1);
    gemm_tile<<<gemmGrid, blk, 0, stream>>>(xb, wqb, nullptr, Qh, 1, QSCALE);
    gemm_tile<<<gemmGrid, blk, 0, stream>>>(xb, wkb, nullptr, Kh, 1, 1.0f);
    gemm_tile<<<gemmGrid, blk, 0, stream>>>(xb, wvb, nullptr, Vh, 1, 1.0f);
    conv_vt_kernel<<<vtGrid, blk, 0, stream>>>(Vh, Vt2);
    attn_mfma<<<attnGrid, blk, 0, stream>>>(Qh, Kh, Vt2, mpt, Op, ml);
    attn_merge<<<mergeGrid, blk, 0, stream>>>(Op, ml, Ob);
    ln_kernel<<<lnGrid, blk, 0, stream>>>(Ob, xb, ln1_w, ln1_b, 1, 1);
    gemm_tile<<<gemmGrid, blk, 0, stream>>>(xb, w1b, fc1_b, h1, 0, 1.0f);
    ln_kernel<<<lnGrid, blk, 0, stream>>>(h1, xb, ln2_w, ln2_b, 1, 1);
    gemm_tile<<<gemmGrid, blk, 0, stream>>>(xb, w2b, fc2_b, h2, 0, 1.0f);
    ln_kernel<<<lnGrid, blk, 0, stream>>>(h2, out, norm_w, norm_b, 0, 0);
}

// Round 7
// 215.875 us; speedup vs baseline: 2.4052x; 1.1212x over previous
//
#include <hip/hip_runtime.h>
#include <cstdint>
#include <cstddef>

#define A_LEN  2048
#define D_DIM  512
#define NHEADS 4
#define HDIM   128
#define B_SZ   4
#define ROWS   8192
#define LN_EPS 1e-5f
#define KSPLIT 2
#define KCHUNK (A_LEN / KSPLIT)   // 1024
#define KTILE  64
#define QBLK   128                // 4 waves x 32 q-rows

typedef __bf16 bf16x8 __attribute__((ext_vector_type(8)));
typedef __bf16 bf16x4 __attribute__((ext_vector_type(4)));
typedef float  f32x4  __attribute__((ext_vector_type(4)));
typedef float  f32x16 __attribute__((ext_vector_type(16)));

static __device__ __forceinline__ uint32_t pkbf(float a, float b) {
    union { __bf16 h[2]; uint32_t u; } t;
    t.h[0] = (__bf16)a; t.h[1] = (__bf16)b;
    return t.u;
}

// ---------------------------------------------------------------------------
// LayerNorm (optional swish), f32 in, bf16 or f32 out. 1 wave / row.
// ---------------------------------------------------------------------------
__global__ __launch_bounds__(256) void ln_kernel(
    const float* __restrict__ in, void* __restrict__ out,
    const float* __restrict__ w, const float* __restrict__ bvec,
    int do_swish, int out_bf16)
{
    int row  = blockIdx.x * 4 + (threadIdx.x >> 6);
    int lane = threadIdx.x & 63;
    const float* x = in + (size_t)row * D_DIM + lane * 8;
    float4 a  = *(const float4*)x;
    float4 b4 = *(const float4*)(x + 4);
    float v[8] = {a.x, a.y, a.z, a.w, b4.x, b4.y, b4.z, b4.w};
    if (do_swish) {
#pragma unroll
        for (int j = 0; j < 8; ++j) v[j] = v[j] / (1.f + __expf(-v[j]));
    }
    float s = 0.f, s2 = 0.f;
#pragma unroll
    for (int j = 0; j < 8; ++j) { s += v[j]; s2 += v[j] * v[j]; }
#pragma unroll
    for (int off = 32; off; off >>= 1) {
        s  += __shfl_xor(s,  off);
        s2 += __shfl_xor(s2, off);
    }
    float mean = s * (1.f / D_DIM);
    float var  = s2 * (1.f / D_DIM) - mean * mean;
    float inv  = rsqrtf(var + LN_EPS);
    const float* wp = w + lane * 8;
    const float* bp = bvec + lane * 8;
    float r[8];
#pragma unroll
    for (int j = 0; j < 8; ++j) r[j] = (v[j] - mean) * inv * wp[j] + bp[j];
    if (out_bf16) {
        bf16x8 ov;
#pragma unroll
        for (int j = 0; j < 8; ++j) ov[j] = (__bf16)r[j];
        *(bf16x8*)((__bf16*)out + (size_t)row * D_DIM + lane * 8) = ov;
    } else {
        float* o = (float*)out + (size_t)row * D_DIM + lane * 8;
        float4 o0 = {r[0], r[1], r[2], r[3]}, o1 = {r[4], r[5], r[6], r[7]};
        *(float4*)o = o0; *(float4*)(o + 4) = o1;
    }
}

// ---------------------------------------------------------------------------
// f32 -> bf16 copy (weights)
// ---------------------------------------------------------------------------
__global__ __launch_bounds__(256) void conv_w_kernel(
    const float* __restrict__ src, __bf16* __restrict__ dst)
{
    size_t i = ((size_t)blockIdx.x * 256 + threadIdx.x) * 8;
    float4 a = *(const float4*)(src + i);
    float4 b = *(const float4*)(src + i + 4);
    bf16x8 o;
    o[0]=(__bf16)a.x; o[1]=(__bf16)a.y; o[2]=(__bf16)a.z; o[3]=(__bf16)a.w;
    o[4]=(__bf16)b.x; o[5]=(__bf16)b.y; o[6]=(__bf16)b.z; o[7]=(__bf16)b.w;
    *(bf16x8*)(dst + i) = o;
}

// ---------------------------------------------------------------------------
// connectivity int32 (B,1,A,A) -> TRANSPOSED bitmask MPT[b][k>>5][q]
// ---------------------------------------------------------------------------
__global__ __launch_bounds__(256) void mask_pack_kernel(
    const int* __restrict__ conn, uint32_t* __restrict__ mpt)
{
    size_t i = (size_t)blockIdx.x * 256 + threadIdx.x;
    uint64_t bal = __ballot(conn[i] != 0);
    int lane = threadIdx.x & 63;
    int b  = (int)(i >> 22);
    int q  = (int)((i >> 11) & (A_LEN - 1));
    int k0 = (int)(i & (A_LEN - 1) & ~(size_t)63);
    if (lane == 0)
        mpt[((size_t)b * 64 + (k0 >> 5)) * A_LEN + q] = (uint32_t)bal;
    else if (lane == 1)
        mpt[((size_t)b * 64 + (k0 >> 5) + 1) * A_LEN + q] = (uint32_t)(bal >> 32);
}

// ---------------------------------------------------------------------------
// Fused QKV GEMM. grid (M/128, 12): y>>2 selects weight, y&3 selects n-tile.
// widx 0: Qh bf16 head-layout * QSCALE; 1: Kh head-layout;
// widx 2: Vt2 [16][64][128][32] tile-major (direct, conv_vt eliminated).
// 128x128 tile, BK=32, 4 waves, reg-staged double-buffered LDS.
// ---------------------------------------------------------------------------
#define GBM 128
#define GBK 32
#define GPAD 40

__global__ __launch_bounds__(256) void gemm_qkv(
    const __bf16* __restrict__ Am,
    const __bf16* __restrict__ Wq, const __bf16* __restrict__ Wk,
    const __bf16* __restrict__ Wv,
    __bf16* __restrict__ Qh, __bf16* __restrict__ Kh, __bf16* __restrict__ Vt2)
{
    const int K = D_DIM;
    __shared__ alignas(16) __bf16 As[2][GBM][GPAD];
    __shared__ alignas(16) __bf16 Ws[2][GBM][GPAD];
    int tid = threadIdx.x;
    int w = tid >> 6, lane = tid & 63;
    int grp = lane >> 4, col = lane & 15;
    int wr = w >> 1, wc = w & 1;
    int m0 = blockIdx.x * GBM;
    int widx = blockIdx.y >> 2;
    int h    = blockIdx.y & 3;       // n-tile == head (128 cols)
    const __bf16* Wm = widx == 0 ? Wq : (widx == 1 ? Wk : Wv);
    int n0 = h * 128;

    int srow = tid >> 1;
    int skc  = (tid & 1) * 16;
    const __bf16* agp = Am + (size_t)(m0 + srow) * K + skc;
    const __bf16* wgp = Wm + (size_t)(n0 + srow) * K + skc;

    uint4 ar0, ar1, wr0, wr1;
    ar0 = *(const uint4*)agp;       ar1 = *(const uint4*)(agp + 8);
    wr0 = *(const uint4*)wgp;       wr1 = *(const uint4*)(wgp + 8);
    *(uint4*)&As[0][srow][skc] = ar0; *(uint4*)&As[0][srow][skc + 8] = ar1;
    *(uint4*)&Ws[0][srow][skc] = wr0; *(uint4*)&Ws[0][srow][skc + 8] = wr1;
    __syncthreads();

    f32x4 acc[4][4] = {};
#pragma unroll 1
    for (int t = 0; t < K / GBK; ++t) {
        int cur = t & 1;
        bool more = (t + 1) < K / GBK;
        if (more) {
            const __bf16* ap = agp + (size_t)(t + 1) * GBK;
            const __bf16* wp = wgp + (size_t)(t + 1) * GBK;
            ar0 = *(const uint4*)ap; ar1 = *(const uint4*)(ap + 8);
            wr0 = *(const uint4*)wp; wr1 = *(const uint4*)(wp + 8);
        }
        bf16x8 af[4], wf[4];
#pragma unroll
        for (int mt = 0; mt < 4; ++mt)
            af[mt] = *(const bf16x8*)&As[cur][wr * 64 + mt * 16 + col][grp * 8];
#pragma unroll
        for (int nt = 0; nt < 4; ++nt)
            wf[nt] = *(const bf16x8*)&Ws[cur][wc * 64 + nt * 16 + col][grp * 8];
        __builtin_amdgcn_s_setprio(1);
#pragma unroll
        for (int mt = 0; mt < 4; ++mt)
#pragma unroll
            for (int nt = 0; nt < 4; ++nt)
                acc[mt][nt] = __builtin_amdgcn_mfma_f32_16x16x32_bf16(
                    af[mt], wf[nt], acc[mt][nt], 0, 0, 0);
        __builtin_amdgcn_s_setprio(0);
        if (more) {
            int nb = cur ^ 1;
            *(uint4*)&As[nb][srow][skc] = ar0; *(uint4*)&As[nb][srow][skc + 8] = ar1;
            *(uint4*)&Ws[nb][srow][skc] = wr0; *(uint4*)&Ws[nb][srow][skc + 8] = wr1;
        }
        __syncthreads();
    }

    const float QSCALE = 0.08838834764831845f;  // 1/sqrt(128)
    if (widx == 2) {
        // Vt2[((bh*64 + kt)*128 + d)*32 + k32], 4 consecutive k32 per acc reg set
        int k32b = (/*wr*64 ≡0 mod32*/ ((0)) + ((0))) + (( ( (0) ))) ; // placeholder
#pragma unroll
        for (int mt = 0; mt < 4; ++mt) {
            int m = m0 + wr * 64 + mt * 16 + grp * 4;
            int b = m >> 11, a = m & (A_LEN - 1);
            int kt = a >> 5, k32 = a & 31;
            int bh = b * NHEADS + h;
#pragma unroll
            for (int nt = 0; nt < 4; ++nt) {
                int d = wc * 64 + nt * 16 + col;
                bf16x4 o;
                o[0] = (__bf16)acc[mt][nt][0]; o[1] = (__bf16)acc[mt][nt][1];
                o[2] = (__bf16)acc[mt][nt][2]; o[3] = (__bf16)acc[mt][nt][3];
                *(bf16x4*)(Vt2 + (((size_t)bh * 64 + kt) * HDIM + d) * 32 + k32) = o;
            }
        }
        (void)k32b;
    } else {
        __bf16* Cb = widx == 0 ? Qh : Kh;
        float sc = widx == 0 ? QSCALE : 1.0f;
#pragma unroll
        for (int nt = 0; nt < 4; ++nt) {
            int d = wc * 64 + nt * 16 + col;
#pragma unroll
            for (int mt = 0; mt < 4; ++mt) {
#pragma unroll
                for (int r = 0; r < 4; ++r) {
                    int m = m0 + wr * 64 + mt * 16 + grp * 4 + r;
                    int b = m >> 11, a = m & (A_LEN - 1);
                    Cb[((size_t)(b * NHEADS + h) * A_LEN + a) * HDIM + d] =
                        (__bf16)(acc[mt][nt][r] * sc);
                }
            }
        }
    }
}

// ---------------------------------------------------------------------------
// fc GEMM: C f32 [8192][512] = A bf16 * W^T bf16 + bias. Same tile engine.
// ---------------------------------------------------------------------------
__global__ __launch_bounds__(256) void gemm_tile(
    const __bf16* __restrict__ Am, const __bf16* __restrict__ Wm,
    const float* __restrict__ bias, float* __restrict__ C)
{
    const int N = D_DIM, K = D_DIM;
    __shared__ alignas(16) __bf16 As[2][GBM][GPAD];
    __shared__ alignas(16) __bf16 Ws[2][GBM][GPAD];
    int tid = threadIdx.x;
    int w = tid >> 6, lane = tid & 63;
    int grp = lane >> 4, col = lane & 15;
    int wr = w >> 1, wc = w & 1;
    int m0 = blockIdx.x * GBM;
    int n0 = blockIdx.y * GBM;

    int srow = tid >> 1;
    int skc  = (tid & 1) * 16;
    const __bf16* agp = Am + (size_t)(m0 + srow) * K + skc;
    const __bf16* wgp = Wm + (size_t)(n0 + srow) * K + skc;

    uint4 ar0, ar1, wr0, wr1;
    ar0 = *(const uint4*)agp;       ar1 = *(const uint4*)(agp + 8);
    wr0 = *(const uint4*)wgp;       wr1 = *(const uint4*)(wgp + 8);
    *(uint4*)&As[0][srow][skc] = ar0; *(uint4*)&As[0][srow][skc + 8] = ar1;
    *(uint4*)&Ws[0][srow][skc] = wr0; *(uint4*)&Ws[0][srow][skc + 8] = wr1;
    __syncthreads();

    f32x4 acc[4][4] = {};
#pragma unroll 1
    for (int t = 0; t < K / GBK; ++t) {
        int cur = t & 1;
        bool more = (t + 1) < K / GBK;
        if (more) {
            const __bf16* ap = agp + (size_t)(t + 1) * GBK;
            const __bf16* wp = wgp + (size_t)(t + 1) * GBK;
            ar0 = *(const uint4*)ap; ar1 = *(const uint4*)(ap + 8);
            wr0 = *(const uint4*)wp; wr1 = *(const uint4*)(wp + 8);
        }
        bf16x8 af[4], wf[4];
#pragma unroll
        for (int mt = 0; mt < 4; ++mt)
            af[mt] = *(const bf16x8*)&As[cur][wr * 64 + mt * 16 + col][grp * 8];
#pragma unroll
        for (int nt = 0; nt < 4; ++nt)
            wf[nt] = *(const bf16x8*)&Ws[cur][wc * 64 + nt * 16 + col][grp * 8];
        __builtin_amdgcn_s_setprio(1);
#pragma unroll
        for (int mt = 0; mt < 4; ++mt)
#pragma unroll
            for (int nt = 0; nt < 4; ++nt)
                acc[mt][nt] = __builtin_amdgcn_mfma_f32_16x16x32_bf16(
                    af[mt], wf[nt], acc[mt][nt], 0, 0, 0);
        __builtin_amdgcn_s_setprio(0);
        if (more) {
            int nb = cur ^ 1;
            *(uint4*)&As[nb][srow][skc] = ar0; *(uint4*)&As[nb][srow][skc + 8] = ar1;
            *(uint4*)&Ws[nb][srow][skc] = wr0; *(uint4*)&Ws[nb][srow][skc + 8] = wr1;
        }
        __syncthreads();
    }

#pragma unroll
    for (int nt = 0; nt < 4; ++nt) {
        int n = n0 + wc * 64 + nt * 16 + col;
        float bv = bias ? bias[n] : 0.f;
#pragma unroll
        for (int mt = 0; mt < 4; ++mt) {
#pragma unroll
            for (int r = 0; r < 4; ++r) {
                int m = m0 + wr * 64 + mt * 16 + grp * 4 + r;
                C[(size_t)m * N + n] = acc[mt][nt][r] + bv;
            }
        }
    }
}

// ---------------------------------------------------------------------------
// Flash attention, swapped-QK^T on mfma_32x32x16, KTILE=64 (2 sub-tiles).
// Block: 4 waves x 32 q-rows; KCHUNK=1024 keys in 64-key tiles, KSPLIT=2.
// Klds[2][64][128] chunk-XOR swizzled; Vlds[2][128][72] (two 36-col subtiles).
// (256,2): needs ~200 VGPR -- do NOT raise waves/EU (round 5 spill lesson).
// ---------------------------------------------------------------------------
__global__ __launch_bounds__(256, 2) void attn_mfma(
    const __bf16* __restrict__ Qh, const __bf16* __restrict__ Kh,
    const __bf16* __restrict__ Vt2, const uint32_t* __restrict__ MPT,
    __bf16* __restrict__ Opart, float2* __restrict__ ml)
{
    int bh = blockIdx.y, b = bh >> 2;
    int split = blockIdx.z;
    int ks0 = split * KCHUNK;
    int tid = threadIdx.x;
    int w = tid >> 6, lane = tid & 63;
    int c31 = lane & 31, hi = lane >> 5;
    int qw = blockIdx.x * QBLK + w * 32;

    __shared__ alignas(16) __bf16 Klds[2][KTILE][128];
    __shared__ alignas(16) __bf16 Vlds[2][HDIM][72];
    __shared__ float Flds[4][32];

    bf16x8 qf[8];
    {
        const __bf16* qptr = Qh + ((size_t)bh * A_LEN + qw + c31) * HDIM + hi * 8;
#pragma unroll
        for (int s = 0; s < 8; ++s) qf[s] = *(const bf16x8*)(qptr + s * 16);
    }

    const __bf16* Ksrc = Kh + ((size_t)bh * A_LEN + ks0) * HDIM;
    const __bf16* Vsrc = Vt2 + ((size_t)bh * 64 + (ks0 >> 5)) * HDIM * 32;
    const uint32_t* mpq = MPT + ((size_t)b * 64 + (ks0 >> 5)) * A_LEN + qw + c31;
    int kxor = c31 & 15;

    float m_run = -1e30f, l_part = 0.f;
    f32x16 oacc[4];
#pragma unroll
    for (int dt = 0; dt < 4; ++dt)
#pragma unroll
        for (int j = 0; j < 16; ++j) oacc[dt][j] = 0.f;

    uint4 kr[4], vr[4];
#pragma unroll
    for (int i = 0; i < 4; ++i) {
        kr[i] = ((const uint4*)Ksrc)[tid + i * 256];
        vr[i] = ((const uint4*)Vsrc)[tid + i * 256];
    }
#pragma unroll
    for (int i = 0; i < 4; ++i) {
        int c = tid + i * 256;                 // uint4 idx 0..1023
        int krow = c >> 4, kch = c & 15;
        *(uint4*)&Klds[0][krow][(kch ^ (krow & 15)) * 8] = kr[i];
        int sub = c >> 9, rem = c & 511;
        int d = rem >> 2, k8 = (rem & 3) * 8;
        *(uint4*)&Vlds[0][d][sub * 36 + k8] = vr[i];
    }
    __syncthreads();

    const int ntl = KCHUNK / KTILE;   // 16
#pragma unroll 1
    for (int t = 0; t < ntl; ++t) {
        int cur = t & 1;
        bool more = (t + 1) < ntl;
        if (more) {
            const __bf16* kp = Ksrc + (size_t)(t + 1) * KTILE * HDIM;
            const __bf16* vp = Vsrc + (size_t)(t + 1) * 2 * HDIM * 32;
#pragma unroll
            for (int i = 0; i < 4; ++i) {
                kr[i] = ((const uint4*)kp)[tid + i * 256];
                vr[i] = ((const uint4*)vp)[tid + i * 256];
            }
        }

        uint32_t mw0 = mpq[(size_t)(2 * t) * A_LEN];
        uint32_t mw1 = mpq[(size_t)(2 * t + 1) * A_LEN];

        // S^T = K Q for both 32-key subtiles
        f32x16 St0, St1;
#pragma unroll
        for (int j = 0; j < 16; ++j) { St0[j] = 0.f; St1[j] = 0.f; }
        __builtin_amdgcn_s_setprio(1);
#pragma unroll
        for (int s = 0; s < 8; ++s) {
            int chk = (((s << 1) | hi) ^ kxor) * 8;
            bf16x8 kf0 = *(const bf16x8*)&Klds[cur][c31][chk];
            bf16x8 kf1 = *(const bf16x8*)&Klds[cur][32 + c31][chk];
            St0 = __builtin_amdgcn_mfma_f32_32x32x16_bf16(kf0, qf[s], St0, 0, 0, 0);
            St1 = __builtin_amdgcn_mfma_f32_32x32x16_bf16(kf1, qf[s], St1, 0, 0, 0);
        }
        __builtin_amdgcn_s_setprio(0);

        // mask in place + in-lane max over 32 S values
        float tmax = -__builtin_inff();
#pragma unroll
        for (int r = 0; r < 16; ++r) {
            int kb = (r & 3) + 8 * (r >> 2) + 4 * hi;
            St0[r] = ((mw0 >> kb) & 1u) ? St0[r] : -__builtin_inff();
            St1[r] = ((mw1 >> kb) & 1u) ? St1[r] : -__builtin_inff();
            tmax = fmaxf(tmax, fmaxf(St0[r], St1[r]));
        }
        tmax = fmaxf(tmax, __shfl_xor(tmax, 32));

        // defer-max rescale (THR=8)
        if (__ballot(tmax > m_run + 8.f)) {
            float mnew = fmaxf(m_run, tmax);
            float f = __expf(m_run - mnew);
            m_run = mnew;
            l_part *= f;
            if (lane < 32) Flds[w][c31] = f;
            __asm__ volatile("s_waitcnt lgkmcnt(0)" ::: "memory");
#pragma unroll
            for (int r = 0; r < 16; ++r) {
                float fr = Flds[w][(r & 3) + 8 * (r >> 2) + 4 * hi];
#pragma unroll
                for (int dt = 0; dt < 4; ++dt) oacc[dt][r] *= fr;
            }
        }

        // P = exp(S - m) in place, partial sum
#pragma unroll
        for (int r = 0; r < 16; ++r) {
            St0[r] = __expf(St0[r] - m_run);
            St1[r] = __expf(St1[r] - m_run);
            l_part += St0[r] + St1[r];
        }

        // pack P -> bf16 A-fragments (per subtile: 2 fragments via lane-swap)
        bf16x8 pa0[2], pa1[2];
#pragma unroll
        for (int sub = 0; sub < 2; ++sub) {
            {
                uint32_t pk01 = pkbf(St0[sub*8+0], St0[sub*8+1]);
                uint32_t pk23 = pkbf(St0[sub*8+2], St0[sub*8+3]);
                uint32_t pk45 = pkbf(St0[sub*8+4], St0[sub*8+5]);
                uint32_t pk67 = pkbf(St0[sub*8+6], St0[sub*8+7]);
                uint32_t s1 = hi ? pk01 : pk45;
                uint32_t s2 = hi ? pk23 : pk67;
                uint32_t r1 = __shfl_xor(s1, 32);
                uint32_t r2 = __shfl_xor(s2, 32);
                union { uint32_t u[4]; bf16x8 v; } fu;
                fu.u[0] = hi ? r1 : pk01;
                fu.u[1] = hi ? r2 : pk23;
                fu.u[2] = hi ? pk45 : r1;
                fu.u[3] = hi ? pk67 : r2;
                pa0[sub] = fu.v;
            }
            {
                uint32_t pk01 = pkbf(St1[sub*8+0], St1[sub*8+1]);
                uint32_t pk23 = pkbf(St1[sub*8+2], St1[sub*8+3]);
                uint32_t pk45 = pkbf(St1[sub*8+4], St1[sub*8+5]);
                uint32_t pk67 = pkbf(St1[sub*8+6], St1[sub*8+7]);
                uint32_t s1 = hi ? pk01 : pk45;
                uint32_t s2 = hi ? pk23 : pk67;
                uint32_t r1 = __shfl_xor(s1, 32);
                uint32_t r2 = __shfl_xor(s2, 32);
                union { uint32_t u[4]; bf16x8 v; } fu;
                fu.u[0] = hi ? r1 : pk01;
                fu.u[1] = hi ? r2 : pk23;
                fu.u[2] = hi ? pk45 : r1;
                fu.u[3] = hi ? pk67 : r2;
                pa1[sub] = fu.v;
            }
        }

        // O += P V (both subtiles)
        __builtin_amdgcn_s_setprio(1);
#pragma unroll
        for (int dt = 0; dt < 4; ++dt) {
            const __bf16* vrow = &Vlds[cur][dt * 32 + c31][0];
            bf16x8 va0 = *(const bf16x8*)(vrow + hi * 8);
            bf16x8 va1 = *(const bf16x8*)(vrow + 16 + hi * 8);
            bf16x8 vb0 = *(const bf16x8*)(vrow + 36 + hi * 8);
            bf16x8 vb1 = *(const bf16x8*)(vrow + 52 + hi * 8);
            oacc[dt] = __builtin_amdgcn_mfma_f32_32x32x16_bf16(pa0[0], va0, oacc[dt], 0, 0, 0);
            oacc[dt] = __builtin_amdgcn_mfma_f32_32x32x16_bf16(pa0[1], va1, oacc[dt], 0, 0, 0);
            oacc[dt] = __builtin_amdgcn_mfma_f32_32x32x16_bf16(pa1[0], vb0, oacc[dt], 0, 0, 0);
            oacc[dt] = __builtin_amdgcn_mfma_f32_32x32x16_bf16(pa1[1], vb1, oacc[dt], 0, 0, 0);
        }
        __builtin_amdgcn_s_setprio(0);

        if (more) {
#pragma unroll
            for (int i = 0; i < 4; ++i) {
                int c = tid + i * 256;
                int krow = c >> 4, kch = c & 15;
                *(uint4*)&Klds[cur ^ 1][krow][(kch ^ (krow & 15)) * 8] = kr[i];
                int sub = c >> 9, rem = c & 511;
                int d = rem >> 2, k8 = (rem & 3) * 8;
                *(uint4*)&Vlds[cur ^ 1][d][sub * 36 + k8] = vr[i];
            }
        }
        __syncthreads();
    }

    float l_tot = l_part + __shfl_xor(l_part, 32);
    if (lane < 32)
        ml[((size_t)split * 16 + bh) * A_LEN + qw + lane] = make_float2(m_run, l_tot);

    __bf16* ob = Opart + (((size_t)split * 16 + bh) * A_LEN + qw) * HDIM;
#pragma unroll
    for (int r = 0; r < 16; ++r) {
        int ql = (r & 3) + 8 * (r >> 2) + 4 * hi;
#pragma unroll
        for (int dt = 0; dt < 4; ++dt)
            ob[(size_t)ql * HDIM + dt * 32 + c31] = (__bf16)oacc[dt][r];
    }
}

// ---------------------------------------------------------------------------
// Fused: merge KSPLIT=2 partials + swish + LN(ln1) -> xb bf16 [8192][512].
// One wave per row; lane covers d512 = lane*8 (head h = d512>>7).
// ---------------------------------------------------------------------------
__global__ __launch_bounds__(256) void attn_merge_ln(
    const __bf16* __restrict__ Opart, const float2* __restrict__ ml,
    const float* __restrict__ lw, const float* __restrict__ lb,
    __bf16* __restrict__ xbout)
{
    int wv = threadIdx.x >> 6, lane = threadIdx.x & 63;
    int ridx = blockIdx.x * 4 + wv;          // 0..8191
    int b = ridx >> 11, a = ridx & (A_LEN - 1);
    int d512 = lane * 8;
    int h = d512 >> 7, d = d512 & 127;
    int bh = b * NHEADS + h;

    float2 ml0 = ml[(size_t)bh * A_LEN + a];
    float2 ml1 = ml[((size_t)16 + bh) * A_LEN + a];
    float M = fmaxf(ml0.x, ml1.x);
    float w0 = __expf(ml0.x - M), w1 = __expf(ml1.x - M);
    float inv = 1.f / (w0 * ml0.y + w1 * ml1.y);

    bf16x8 v0 = *(const bf16x8*)(Opart + ((size_t)bh * A_LEN + a) * HDIM + d);
    bf16x8 v1 = *(const bf16x8*)(Opart + (((size_t)16 + bh) * A_LEN + a) * HDIM + d);
    float v[8];
#pragma unroll
    for (int j = 0; j < 8; ++j) {
        float o = (w0 * (float)v0[j] + w1 * (float)v1[j]) * inv;
        v[j] = o / (1.f + __expf(-o));       // swish
    }
    float s = 0.f, s2 = 0.f;
#pragma unroll
    for (int j = 0; j < 8; ++j) { s += v[j]; s2 += v[j] * v[j]; }
#pragma unroll
    for (int off = 32; off; off >>= 1) {
        s  += __shfl_xor(s,  off);
        s2 += __shfl_xor(s2, off);
    }
    float mean = s * (1.f / D_DIM);
    float var  = s2 * (1.f / D_DIM) - mean * mean;
    float rinv = rsqrtf(var + LN_EPS);
    bf16x8 ov;
#pragma unroll
    for (int j = 0; j < 8; ++j)
        ov[j] = (__bf16)((v[j] - mean) * rinv * lw[d512 + j] + lb[d512 + j]);
    *(bf16x8*)(xbout + (size_t)ridx * D_DIM + d512) = ov;
}

// ---------------------------------------------------------------------------
extern "C" void kernel_launch(void* const* d_in, const int* in_sizes, int n_in,
                              void* d_out, int out_size, void* d_ws, size_t ws_size,
                              hipStream_t stream)
{
    const float* x      = (const float*)d_in[0];
    const int*   conn   = (const int*)d_in[1];
    const float* Wq     = (const float*)d_in[2];
    const float* Wk     = (const float*)d_in[3];
    const float* Wv     = (const float*)d_in[4];
    const float* norm_w = (const float*)d_in[5];
    const float* norm_b = (const float*)d_in[6];
    const float* ln1_w  = (const float*)d_in[7];
    const float* ln1_b  = (const float*)d_in[8];
    const float* fc1_w  = (const float*)d_in[9];
    const float* fc1_b  = (const float*)d_in[10];
    const float* ln2_w  = (const float*)d_in[11];
    const float* ln2_b  = (const float*)d_in[12];
    const float* fc2_w  = (const float*)d_in[13];
    const float* fc2_b  = (const float*)d_in[14];
    float* out = (float*)d_out;

    char* wsb = (char*)d_ws;
    const size_t WELEM = (size_t)D_DIM * D_DIM;
    const size_t MB = (size_t)1 << 20;
    __bf16*   wqb = (__bf16*)(wsb);                          // [0,3) weights bf16
    __bf16*   wkb = wqb + WELEM;
    __bf16*   wvb = wkb + WELEM;
    __bf16*   w1b = wvb + WELEM;
    __bf16*   w2b = w1b + WELEM;
    uint32_t* mpt = (uint32_t*)(wsb + 3 * MB);               // 2MB  [3,5)
    float2*   ml  = (float2*)(wsb + 5 * MB);                 // .5MB [5,6)
    __bf16*   xb  = (__bf16*)(wsb + 6 * MB);                 // 8MB  [6,14)
    __bf16*   Qh  = (__bf16*)(wsb + 14 * MB);                // 8MB  [14,22)
    __bf16*   Kh  = (__bf16*)(wsb + 22 * MB);                // 8MB  [22,30)
    __bf16*   Vt2 = (__bf16*)(wsb + 30 * MB);                // 8MB  [30,38)
    __bf16*   Op  = (__bf16*)(wsb + 38 * MB);                // 16MB [38,54)
    float*    h1  = (float*)(wsb + 14 * MB);                 // 16MB alias Qh/Kh
    float*    h2  = (float*)(wsb + 38 * MB);                 // 16MB alias Op

    dim3 blk(256);
    dim3 lnGrid(ROWS / 4);
    dim3 qkvGrid(ROWS / GBM, 12);                            // 768 blocks
    dim3 fcGrid(ROWS / GBM, D_DIM / GBM);                    // 256 blocks
    dim3 attnGrid(A_LEN / QBLK, B_SZ * NHEADS, KSPLIT);      // 512 blocks
    dim3 mergeGrid(ROWS / 4);
    dim3 wGrid(WELEM / 8 / 256);
    dim3 mpGrid((size_t)B_SZ * A_LEN * A_LEN / 256);

    conv_w_kernel<<<wGrid, blk, 0, stream>>>(Wq, wqb);
    conv_w_kernel<<<wGrid, blk, 0, stream>>>(Wk, wkb);
    conv_w_kernel<<<wGrid, blk, 0, stream>>>(Wv, wvb);
    conv_w_kernel<<<wGrid, blk, 0, stream>>>(fc1_w, w1b);
    conv_w_kernel<<<wGrid, blk, 0, stream>>>(fc2_w, w2b);
    mask_pack_kernel<<<mpGrid, blk, 0, stream>>>(conn, mpt);

    ln_kernel<<<lnGrid, blk, 0, stream>>>(x, xb, norm_w, norm_b, 0, 1);
    gemm_qkv<<<qkvGrid, blk, 0, stream>>>(xb, wqb, wkb, wvb, Qh, Kh, Vt2);
    attn_mfma<<<attnGrid, blk, 0, stream>>>(Qh, Kh, Vt2, mpt, Op, ml);
    attn_merge_ln<<<mergeGrid, blk, 0, stream>>>(Op, ml, ln1_w, ln1_b, xb);
    gemm_tile<<<fcGrid, blk, 0, stream>>>(xb, w1b, fc1_b, h1);
    ln_kernel<<<lnGrid, blk, 0, stream>>>(h1, xb, ln2_w, ln2_b, 1, 1);
    gemm_tile<<<fcGrid, blk, 0, stream>>>(xb, w2b, fc2_b, h2);
    ln_kernel<<<lnGrid, blk, 0, stream>>>(h2, out, norm_w, norm_b, 0, 0);
}

// Round 8
// 197.872 us; speedup vs baseline: 2.6241x; 1.0910x over previous
//
#include <hip/hip_runtime.h>
#include <cstdint>
#include <cstddef>

#define A_LEN  2048
#define D_DIM  512
#define NHEADS 4
#define HDIM   128
#define B_SZ   4
#define ROWS   8192
#define LN_EPS 1e-5f
#define KSPLIT 2
#define KCHUNK (A_LEN / KSPLIT)   // 1024
#define KTILE  32
#define QBLK   128                // 4 waves x 32 q-rows

typedef __bf16 bf16x8 __attribute__((ext_vector_type(8)));
typedef __bf16 bf16x4 __attribute__((ext_vector_type(4)));
typedef float  f32x4  __attribute__((ext_vector_type(4)));
typedef float  f32x16 __attribute__((ext_vector_type(16)));

static __device__ __forceinline__ uint32_t pkbf(float a, float b) {
    union { __bf16 h[2]; uint32_t u; } t;
    t.h[0] = (__bf16)a; t.h[1] = (__bf16)b;
    return t.u;
}

// ---------------------------------------------------------------------------
// LayerNorm (optional swish), f32 in, bf16 or f32 out. 1 wave / row.
// ---------------------------------------------------------------------------
__global__ __launch_bounds__(256) void ln_kernel(
    const float* __restrict__ in, void* __restrict__ out,
    const float* __restrict__ w, const float* __restrict__ bvec,
    int do_swish, int out_bf16)
{
    int row  = blockIdx.x * 4 + (threadIdx.x >> 6);
    int lane = threadIdx.x & 63;
    const float* x = in + (size_t)row * D_DIM + lane * 8;
    float4 a  = *(const float4*)x;
    float4 b4 = *(const float4*)(x + 4);
    float v[8] = {a.x, a.y, a.z, a.w, b4.x, b4.y, b4.z, b4.w};
    if (do_swish) {
#pragma unroll
        for (int j = 0; j < 8; ++j) v[j] = v[j] / (1.f + __expf(-v[j]));
    }
    float s = 0.f, s2 = 0.f;
#pragma unroll
    for (int j = 0; j < 8; ++j) { s += v[j]; s2 += v[j] * v[j]; }
#pragma unroll
    for (int off = 32; off; off >>= 1) {
        s  += __shfl_xor(s,  off);
        s2 += __shfl_xor(s2, off);
    }
    float mean = s * (1.f / D_DIM);
    float var  = s2 * (1.f / D_DIM) - mean * mean;
    float inv  = rsqrtf(var + LN_EPS);
    const float* wp = w + lane * 8;
    const float* bp = bvec + lane * 8;
    float r[8];
#pragma unroll
    for (int j = 0; j < 8; ++j) r[j] = (v[j] - mean) * inv * wp[j] + bp[j];
    if (out_bf16) {
        bf16x8 ov;
#pragma unroll
        for (int j = 0; j < 8; ++j) ov[j] = (__bf16)r[j];
        *(bf16x8*)((__bf16*)out + (size_t)row * D_DIM + lane * 8) = ov;
    } else {
        float* o = (float*)out + (size_t)row * D_DIM + lane * 8;
        float4 o0 = {r[0], r[1], r[2], r[3]}, o1 = {r[4], r[5], r[6], r[7]};
        *(float4*)o = o0; *(float4*)(o + 4) = o1;
    }
}

// ---------------------------------------------------------------------------
// f32 -> bf16 copy for all 5 weights in one launch (blockIdx.y selects)
// ---------------------------------------------------------------------------
__global__ __launch_bounds__(256) void conv_w5_kernel(
    const float* __restrict__ s0, const float* __restrict__ s1,
    const float* __restrict__ s2, const float* __restrict__ s3,
    const float* __restrict__ s4, __bf16* __restrict__ dst)
{
    int widx = blockIdx.y;
    const float* src = widx == 0 ? s0 : widx == 1 ? s1 : widx == 2 ? s2
                     : widx == 3 ? s3 : s4;
    size_t i = ((size_t)blockIdx.x * 256 + threadIdx.x) * 8;
    float4 a = *(const float4*)(src + i);
    float4 b = *(const float4*)(src + i + 4);
    bf16x8 o;
    o[0]=(__bf16)a.x; o[1]=(__bf16)a.y; o[2]=(__bf16)a.z; o[3]=(__bf16)a.w;
    o[4]=(__bf16)b.x; o[5]=(__bf16)b.y; o[6]=(__bf16)b.z; o[7]=(__bf16)b.w;
    *(bf16x8*)(dst + (size_t)widx * D_DIM * D_DIM + i) = o;
}

// ---------------------------------------------------------------------------
// connectivity int32 (B,1,A,A) -> TRANSPOSED bitmask MPT[b][k>>5][q]
// ---------------------------------------------------------------------------
__global__ __launch_bounds__(256) void mask_pack_kernel(
    const int* __restrict__ conn, uint32_t* __restrict__ mpt)
{
    size_t i = (size_t)blockIdx.x * 256 + threadIdx.x;
    uint64_t bal = __ballot(conn[i] != 0);
    int lane = threadIdx.x & 63;
    int b  = (int)(i >> 22);
    int q  = (int)((i >> 11) & (A_LEN - 1));
    int k0 = (int)(i & (A_LEN - 1) & ~(size_t)63);
    if (lane == 0)
        mpt[((size_t)b * 64 + (k0 >> 5)) * A_LEN + q] = (uint32_t)bal;
    else if (lane == 1)
        mpt[((size_t)b * 64 + (k0 >> 5) + 1) * A_LEN + q] = (uint32_t)(bal >> 32);
}

// ---------------------------------------------------------------------------
// Fused QKV GEMM. grid (M/128, 12): y>>2 selects weight, y&3 selects head.
// widx 0: Qh bf16 head-layout * QSCALE; 1: Kh head-layout;
// widx 2: Vt2 [16][64][128][32] tile-major.
// ---------------------------------------------------------------------------
#define GBM 128
#define GBK 32
#define GPAD 40

__global__ __launch_bounds__(256) void gemm_qkv(
    const __bf16* __restrict__ Am, const __bf16* __restrict__ Wall,
    __bf16* __restrict__ Qh, __bf16* __restrict__ Kh, __bf16* __restrict__ Vt2)
{
    const int K = D_DIM;
    __shared__ alignas(16) __bf16 As[2][GBM][GPAD];
    __shared__ alignas(16) __bf16 Ws[2][GBM][GPAD];
    int tid = threadIdx.x;
    int w = tid >> 6, lane = tid & 63;
    int grp = lane >> 4, col = lane & 15;
    int wr = w >> 1, wc = w & 1;
    int m0 = blockIdx.x * GBM;
    int widx = blockIdx.y >> 2;
    int h    = blockIdx.y & 3;
    const __bf16* Wm = Wall + (size_t)widx * D_DIM * D_DIM;
    int n0 = h * 128;

    int srow = tid >> 1;
    int skc  = (tid & 1) * 16;
    const __bf16* agp = Am + (size_t)(m0 + srow) * K + skc;
    const __bf16* wgp = Wm + (size_t)(n0 + srow) * K + skc;

    uint4 ar0, ar1, wr0, wr1;
    ar0 = *(const uint4*)agp;       ar1 = *(const uint4*)(agp + 8);
    wr0 = *(const uint4*)wgp;       wr1 = *(const uint4*)(wgp + 8);
    *(uint4*)&As[0][srow][skc] = ar0; *(uint4*)&As[0][srow][skc + 8] = ar1;
    *(uint4*)&Ws[0][srow][skc] = wr0; *(uint4*)&Ws[0][srow][skc + 8] = wr1;
    __syncthreads();

    f32x4 acc[4][4] = {};
#pragma unroll 1
    for (int t = 0; t < K / GBK; ++t) {
        int cur = t & 1;
        bool more = (t + 1) < K / GBK;
        if (more) {
            const __bf16* ap = agp + (size_t)(t + 1) * GBK;
            const __bf16* wp = wgp + (size_t)(t + 1) * GBK;
            ar0 = *(const uint4*)ap; ar1 = *(const uint4*)(ap + 8);
            wr0 = *(const uint4*)wp; wr1 = *(const uint4*)(wp + 8);
        }
        bf16x8 af[4], wf[4];
#pragma unroll
        for (int mt = 0; mt < 4; ++mt)
            af[mt] = *(const bf16x8*)&As[cur][wr * 64 + mt * 16 + col][grp * 8];
#pragma unroll
        for (int nt = 0; nt < 4; ++nt)
            wf[nt] = *(const bf16x8*)&Ws[cur][wc * 64 + nt * 16 + col][grp * 8];
        __builtin_amdgcn_s_setprio(1);
#pragma unroll
        for (int mt = 0; mt < 4; ++mt)
#pragma unroll
            for (int nt = 0; nt < 4; ++nt)
                acc[mt][nt] = __builtin_amdgcn_mfma_f32_16x16x32_bf16(
                    af[mt], wf[nt], acc[mt][nt], 0, 0, 0);
        __builtin_amdgcn_s_setprio(0);
        if (more) {
            int nb = cur ^ 1;
            *(uint4*)&As[nb][srow][skc] = ar0; *(uint4*)&As[nb][srow][skc + 8] = ar1;
            *(uint4*)&Ws[nb][srow][skc] = wr0; *(uint4*)&Ws[nb][srow][skc + 8] = wr1;
        }
        __syncthreads();
    }

    const float QSCALE = 0.08838834764831845f;  // 1/sqrt(128)
    if (widx == 2) {
#pragma unroll
        for (int mt = 0; mt < 4; ++mt) {
            int m = m0 + wr * 64 + mt * 16 + grp * 4;
            int b = m >> 11, a = m & (A_LEN - 1);
            int kt = a >> 5, k32 = a & 31;
            int bh = b * NHEADS + h;
#pragma unroll
            for (int nt = 0; nt < 4; ++nt) {
                int d = wc * 64 + nt * 16 + col;
                bf16x4 o;
                o[0] = (__bf16)acc[mt][nt][0]; o[1] = (__bf16)acc[mt][nt][1];
                o[2] = (__bf16)acc[mt][nt][2]; o[3] = (__bf16)acc[mt][nt][3];
                *(bf16x4*)(Vt2 + (((size_t)bh * 64 + kt) * HDIM + d) * 32 + k32) = o;
            }
        }
    } else {
        __bf16* Cb = widx == 0 ? Qh : Kh;
        float sc = widx == 0 ? QSCALE : 1.0f;
#pragma unroll
        for (int nt = 0; nt < 4; ++nt) {
            int d = wc * 64 + nt * 16 + col;
#pragma unroll
            for (int mt = 0; mt < 4; ++mt) {
#pragma unroll
                for (int r = 0; r < 4; ++r) {
                    int m = m0 + wr * 64 + mt * 16 + grp * 4 + r;
                    int b = m >> 11, a = m & (A_LEN - 1);
                    Cb[((size_t)(b * NHEADS + h) * A_LEN + a) * HDIM + d] =
                        (__bf16)(acc[mt][nt][r] * sc);
                }
            }
        }
    }
}

// ---------------------------------------------------------------------------
// fc GEMM: C f32 [8192][512] = A bf16 * W^T bf16 + bias.
// ---------------------------------------------------------------------------
__global__ __launch_bounds__(256) void gemm_tile(
    const __bf16* __restrict__ Am, const __bf16* __restrict__ Wm,
    const float* __restrict__ bias, float* __restrict__ C)
{
    const int N = D_DIM, K = D_DIM;
    __shared__ alignas(16) __bf16 As[2][GBM][GPAD];
    __shared__ alignas(16) __bf16 Ws[2][GBM][GPAD];
    int tid = threadIdx.x;
    int w = tid >> 6, lane = tid & 63;
    int grp = lane >> 4, col = lane & 15;
    int wr = w >> 1, wc = w & 1;
    int m0 = blockIdx.x * GBM;
    int n0 = blockIdx.y * GBM;

    int srow = tid >> 1;
    int skc  = (tid & 1) * 16;
    const __bf16* agp = Am + (size_t)(m0 + srow) * K + skc;
    const __bf16* wgp = Wm + (size_t)(n0 + srow) * K + skc;

    uint4 ar0, ar1, wr0, wr1;
    ar0 = *(const uint4*)agp;       ar1 = *(const uint4*)(agp + 8);
    wr0 = *(const uint4*)wgp;       wr1 = *(const uint4*)(wgp + 8);
    *(uint4*)&As[0][srow][skc] = ar0; *(uint4*)&As[0][srow][skc + 8] = ar1;
    *(uint4*)&Ws[0][srow][skc] = wr0; *(uint4*)&Ws[0][srow][skc + 8] = wr1;
    __syncthreads();

    f32x4 acc[4][4] = {};
#pragma unroll 1
    for (int t = 0; t < K / GBK; ++t) {
        int cur = t & 1;
        bool more = (t + 1) < K / GBK;
        if (more) {
            const __bf16* ap = agp + (size_t)(t + 1) * GBK;
            const __bf16* wp = wgp + (size_t)(t + 1) * GBK;
            ar0 = *(const uint4*)ap; ar1 = *(const uint4*)(ap + 8);
            wr0 = *(const uint4*)wp; wr1 = *(const uint4*)(wp + 8);
        }
        bf16x8 af[4], wf[4];
#pragma unroll
        for (int mt = 0; mt < 4; ++mt)
            af[mt] = *(const bf16x8*)&As[cur][wr * 64 + mt * 16 + col][grp * 8];
#pragma unroll
        for (int nt = 0; nt < 4; ++nt)
            wf[nt] = *(const bf16x8*)&Ws[cur][wc * 64 + nt * 16 + col][grp * 8];
        __builtin_amdgcn_s_setprio(1);
#pragma unroll
        for (int mt = 0; mt < 4; ++mt)
#pragma unroll
            for (int nt = 0; nt < 4; ++nt)
                acc[mt][nt] = __builtin_amdgcn_mfma_f32_16x16x32_bf16(
                    af[mt], wf[nt], acc[mt][nt], 0, 0, 0);
        __builtin_amdgcn_s_setprio(0);
        if (more) {
            int nb = cur ^ 1;
            *(uint4*)&As[nb][srow][skc] = ar0; *(uint4*)&As[nb][srow][skc + 8] = ar1;
            *(uint4*)&Ws[nb][srow][skc] = wr0; *(uint4*)&Ws[nb][srow][skc + 8] = wr1;
        }
        __syncthreads();
    }

#pragma unroll
    for (int nt = 0; nt < 4; ++nt) {
        int n = n0 + wc * 64 + nt * 16 + col;
        float bv = bias ? bias[n] : 0.f;
#pragma unroll
        for (int mt = 0; mt < 4; ++mt) {
#pragma unroll
            for (int r = 0; r < 4; ++r) {
                int m = m0 + wr * 64 + mt * 16 + grp * 4 + r;
                C[(size_t)m * N + n] = acc[mt][nt][r] + bv;
            }
        }
    }
}

// ---------------------------------------------------------------------------
// Flash attention, swapped-QK^T on mfma_32x32x16: lane-local softmax.
// Round-6 no-spill body: KTILE=32, KSPLIT=2 (KCHUNK=1024, 32 tiles).
// Klds[2][32][128] chunk-XOR swizzled; Vlds[2][128][40].
// KTILE=64 (round 7) spilled ~200MB scratch -- keep footprint at this level.
// ---------------------------------------------------------------------------
__global__ __launch_bounds__(256, 2) void attn_mfma(
    const __bf16* __restrict__ Qh, const __bf16* __restrict__ Kh,
    const __bf16* __restrict__ Vt2, const uint32_t* __restrict__ MPT,
    __bf16* __restrict__ Opart, float2* __restrict__ ml)
{
    int bh = blockIdx.y, b = bh >> 2;
    int split = blockIdx.z;
    int ks0 = split * KCHUNK;
    int tid = threadIdx.x;
    int w = tid >> 6, lane = tid & 63;
    int c31 = lane & 31, hi = lane >> 5;
    int qw = blockIdx.x * QBLK + w * 32;

    __shared__ alignas(16) __bf16 Klds[2][KTILE][128];
    __shared__ alignas(16) __bf16 Vlds[2][HDIM][40];
    __shared__ float Flds[4][32];

    bf16x8 qf[8];
    {
        const __bf16* qptr = Qh + ((size_t)bh * A_LEN + qw + c31) * HDIM + hi * 8;
#pragma unroll
        for (int s = 0; s < 8; ++s) qf[s] = *(const bf16x8*)(qptr + s * 16);
    }

    const __bf16* Ksrc = Kh + ((size_t)bh * A_LEN + ks0) * HDIM;
    const __bf16* Vsrc = Vt2 + ((size_t)bh * 64 + (ks0 >> 5)) * HDIM * 32;
    const uint32_t* mpq = MPT + ((size_t)b * 64 + (ks0 >> 5)) * A_LEN + qw + c31;
    int kxor = c31 & 15;

    float m_run = -1e30f, l_part = 0.f;
    f32x16 oacc[4];
#pragma unroll
    for (int dt = 0; dt < 4; ++dt)
#pragma unroll
        for (int j = 0; j < 16; ++j) oacc[dt][j] = 0.f;

    uint4 kr[2], vr[2];
#pragma unroll
    for (int i = 0; i < 2; ++i) {
        kr[i] = ((const uint4*)Ksrc)[tid + i * 256];
        vr[i] = ((const uint4*)Vsrc)[tid + i * 256];
    }
#pragma unroll
    for (int i = 0; i < 2; ++i) {
        int c = tid + i * 256;
        int krow = c >> 4, kch = c & 15;
        *(uint4*)&Klds[0][krow][(kch ^ (krow & 15)) * 8] = kr[i];
        *(uint4*)&Vlds[0][c >> 2][(c & 3) * 8] = vr[i];
    }
    __syncthreads();

    const int ntl = KCHUNK / KTILE;   // 32
#pragma unroll 1
    for (int t = 0; t < ntl; ++t) {
        int cur = t & 1;
        bool more = (t + 1) < ntl;
        if (more) {
#pragma unroll
            for (int i = 0; i < 2; ++i) {
                kr[i] = ((const uint4*)(Ksrc + (size_t)(t + 1) * KTILE * HDIM))[tid + i * 256];
                vr[i] = ((const uint4*)(Vsrc + (size_t)(t + 1) * HDIM * 32))[tid + i * 256];
            }
        }

        uint32_t mw = mpq[(size_t)t * A_LEN];

        // S^T = K Q : S[k=(r&3)+8*(r>>2)+4*hi][q=c31]
        f32x16 St;
#pragma unroll
        for (int j = 0; j < 16; ++j) St[j] = 0.f;
        __builtin_amdgcn_s_setprio(1);
#pragma unroll
        for (int s = 0; s < 8; ++s) {
            bf16x8 kf = *(const bf16x8*)&Klds[cur][c31][(((s << 1) | hi) ^ kxor) * 8];
            St = __builtin_amdgcn_mfma_f32_32x32x16_bf16(kf, qf[s], St, 0, 0, 0);
        }
        __builtin_amdgcn_s_setprio(0);

        // mask in place + in-lane row max
        float tmax = -__builtin_inff();
#pragma unroll
        for (int r = 0; r < 16; ++r) {
            int kb = (r & 3) + 8 * (r >> 2) + 4 * hi;
            St[r] = ((mw >> kb) & 1u) ? St[r] : -__builtin_inff();
            tmax = fmaxf(tmax, St[r]);
        }
        tmax = fmaxf(tmax, __shfl_xor(tmax, 32));

        // defer-max rescale (THR=8)
        if (__ballot(tmax > m_run + 8.f)) {
            float mnew = fmaxf(m_run, tmax);
            float f = __expf(m_run - mnew);
            m_run = mnew;
            l_part *= f;
            if (lane < 32) Flds[w][c31] = f;
            __asm__ volatile("s_waitcnt lgkmcnt(0)" ::: "memory");
#pragma unroll
            for (int r = 0; r < 16; ++r) {
                float fr = Flds[w][(r & 3) + 8 * (r >> 2) + 4 * hi];
#pragma unroll
                for (int dt = 0; dt < 4; ++dt) oacc[dt][r] *= fr;
            }
        }

        // P = exp(S - m), in-lane partial sum
        float p[16];
#pragma unroll
        for (int r = 0; r < 16; ++r) {
            p[r] = __expf(St[r] - m_run);
            l_part += p[r];
        }

        // pack P -> bf16, lane-pair exchange -> A-operand fragments
        bf16x8 pa[2];
#pragma unroll
        for (int sub = 0; sub < 2; ++sub) {
            const float* pp = p + sub * 8;
            uint32_t pk01 = pkbf(pp[0], pp[1]);
            uint32_t pk23 = pkbf(pp[2], pp[3]);
            uint32_t pk45 = pkbf(pp[4], pp[5]);
            uint32_t pk67 = pkbf(pp[6], pp[7]);
            uint32_t s1 = hi ? pk01 : pk45;
            uint32_t s2 = hi ? pk23 : pk67;
            uint32_t r1 = __shfl_xor(s1, 32);
            uint32_t r2 = __shfl_xor(s2, 32);
            union { uint32_t u[4]; bf16x8 v; } fu;
            fu.u[0] = hi ? r1 : pk01;
            fu.u[1] = hi ? r2 : pk23;
            fu.u[2] = hi ? pk45 : r1;
            fu.u[3] = hi ? pk67 : r2;
            pa[sub] = fu.v;
        }

        // O += P V
        __builtin_amdgcn_s_setprio(1);
#pragma unroll
        for (int dt = 0; dt < 4; ++dt) {
            bf16x8 v0 = *(const bf16x8*)&Vlds[cur][dt * 32 + c31][hi * 8];
            bf16x8 v1 = *(const bf16x8*)&Vlds[cur][dt * 32 + c31][16 + hi * 8];
            oacc[dt] = __builtin_amdgcn_mfma_f32_32x32x16_bf16(pa[0], v0, oacc[dt], 0, 0, 0);
            oacc[dt] = __builtin_amdgcn_mfma_f32_32x32x16_bf16(pa[1], v1, oacc[dt], 0, 0, 0);
        }
        __builtin_amdgcn_s_setprio(0);

        if (more) {
#pragma unroll
            for (int i = 0; i < 2; ++i) {
                int c = tid + i * 256;
                int krow = c >> 4, kch = c & 15;
                *(uint4*)&Klds[cur ^ 1][krow][(kch ^ (krow & 15)) * 8] = kr[i];
                *(uint4*)&Vlds[cur ^ 1][c >> 2][(c & 3) * 8] = vr[i];
            }
        }
        __syncthreads();
    }

    float l_tot = l_part + __shfl_xor(l_part, 32);
    if (lane < 32)
        ml[((size_t)split * 16 + bh) * A_LEN + qw + lane] = make_float2(m_run, l_tot);

    __bf16* ob = Opart + (((size_t)split * 16 + bh) * A_LEN + qw) * HDIM;
#pragma unroll
    for (int r = 0; r < 16; ++r) {
        int ql = (r & 3) + 8 * (r >> 2) + 4 * hi;
#pragma unroll
        for (int dt = 0; dt < 4; ++dt)
            ob[(size_t)ql * HDIM + dt * 32 + c31] = (__bf16)oacc[dt][r];
    }
}

// ---------------------------------------------------------------------------
// Fused: merge KSPLIT=2 partials + swish + LN(ln1) -> xb bf16 [8192][512].
// ---------------------------------------------------------------------------
__global__ __launch_bounds__(256) void attn_merge_ln(
    const __bf16* __restrict__ Opart, const float2* __restrict__ ml,
    const float* __restrict__ lw, const float* __restrict__ lb,
    __bf16* __restrict__ xbout)
{
    int wv = threadIdx.x >> 6, lane = threadIdx.x & 63;
    int ridx = blockIdx.x * 4 + wv;          // 0..8191
    int b = ridx >> 11, a = ridx & (A_LEN - 1);
    int d512 = lane * 8;
    int h = d512 >> 7, d = d512 & 127;
    int bh = b * NHEADS + h;

    float2 ml0 = ml[(size_t)bh * A_LEN + a];
    float2 ml1 = ml[((size_t)16 + bh) * A_LEN + a];
    float M = fmaxf(ml0.x, ml1.x);
    float w0 = __expf(ml0.x - M), w1 = __expf(ml1.x - M);
    float inv = 1.f / (w0 * ml0.y + w1 * ml1.y);

    bf16x8 v0 = *(const bf16x8*)(Opart + ((size_t)bh * A_LEN + a) * HDIM + d);
    bf16x8 v1 = *(const bf16x8*)(Opart + (((size_t)16 + bh) * A_LEN + a) * HDIM + d);
    float v[8];
#pragma unroll
    for (int j = 0; j < 8; ++j) {
        float o = (w0 * (float)v0[j] + w1 * (float)v1[j]) * inv;
        v[j] = o / (1.f + __expf(-o));       // swish
    }
    float s = 0.f, s2 = 0.f;
#pragma unroll
    for (int j = 0; j < 8; ++j) { s += v[j]; s2 += v[j] * v[j]; }
#pragma unroll
    for (int off = 32; off; off >>= 1) {
        s  += __shfl_xor(s,  off);
        s2 += __shfl_xor(s2, off);
    }
    float mean = s * (1.f / D_DIM);
    float var  = s2 * (1.f / D_DIM) - mean * mean;
    float rinv = rsqrtf(var + LN_EPS);
    bf16x8 ov;
#pragma unroll
    for (int j = 0; j < 8; ++j)
        ov[j] = (__bf16)((v[j] - mean) * rinv * lw[d512 + j] + lb[d512 + j]);
    *(bf16x8*)(xbout + (size_t)ridx * D_DIM + d512) = ov;
}

// ---------------------------------------------------------------------------
extern "C" void kernel_launch(void* const* d_in, const int* in_sizes, int n_in,
                              void* d_out, int out_size, void* d_ws, size_t ws_size,
                              hipStream_t stream)
{
    const float* x      = (const float*)d_in[0];
    const int*   conn   = (const int*)d_in[1];
    const float* Wq     = (const float*)d_in[2];
    const float* Wk     = (const float*)d_in[3];
    const float* Wv     = (const float*)d_in[4];
    const float* norm_w = (const float*)d_in[5];
    const float* norm_b = (const float*)d_in[6];
    const float* ln1_w  = (const float*)d_in[7];
    const float* ln1_b  = (const float*)d_in[8];
    const float* fc1_w  = (const float*)d_in[9];
    const float* fc1_b  = (const float*)d_in[10];
    const float* ln2_w  = (const float*)d_in[11];
    const float* ln2_b  = (const float*)d_in[12];
    const float* fc2_w  = (const float*)d_in[13];
    const float* fc2_b  = (const float*)d_in[14];
    float* out = (float*)d_out;

    char* wsb = (char*)d_ws;
    const size_t WELEM = (size_t)D_DIM * D_DIM;
    const size_t MB = (size_t)1 << 20;
    __bf16*   wall = (__bf16*)(wsb);                         // 5 weights bf16 [0,3)
    uint32_t* mpt = (uint32_t*)(wsb + 3 * MB);               // 2MB  [3,5)
    float2*   ml  = (float2*)(wsb + 5 * MB);                 // .5MB [5,6)
    __bf16*   xb  = (__bf16*)(wsb + 6 * MB);                 // 8MB  [6,14)
    __bf16*   Qh  = (__bf16*)(wsb + 14 * MB);                // 8MB  [14,22)
    __bf16*   Kh  = (__bf16*)(wsb + 22 * MB);                // 8MB  [22,30)
    __bf16*   Vt2 = (__bf16*)(wsb + 30 * MB);                // 8MB  [30,38)
    __bf16*   Op  = (__bf16*)(wsb + 38 * MB);                // 16MB [38,54)
    float*    h1  = (float*)(wsb + 14 * MB);                 // 16MB alias Qh/Kh
    float*    h2  = (float*)(wsb + 38 * MB);                 // 16MB alias Op

    dim3 blk(256);
    dim3 lnGrid(ROWS / 4);
    dim3 cwGrid(WELEM / 8 / 256, 5);
    dim3 qkvGrid(ROWS / GBM, 12);                            // 768 blocks
    dim3 fcGrid(ROWS / GBM, D_DIM / GBM);                    // 256 blocks
    dim3 attnGrid(A_LEN / QBLK, B_SZ * NHEADS, KSPLIT);      // 512 blocks
    dim3 mergeGrid(ROWS / 4);
    dim3 mpGrid((size_t)B_SZ * A_LEN * A_LEN / 256);

    conv_w5_kernel<<<cwGrid, blk, 0, stream>>>(Wq, Wk, Wv, fc1_w, fc2_w, wall);
    mask_pack_kernel<<<mpGrid, blk, 0, stream>>>(conn, mpt);

    ln_kernel<<<lnGrid, blk, 0, stream>>>(x, xb, norm_w, norm_b, 0, 1);
    gemm_qkv<<<qkvGrid, blk, 0, stream>>>(xb, wall, Qh, Kh, Vt2);
    attn_mfma<<<attnGrid, blk, 0, stream>>>(Qh, Kh, Vt2, mpt, Op, ml);
    attn_merge_ln<<<mergeGrid, blk, 0, stream>>>(Op, ml, ln1_w, ln1_b, xb);
    gemm_tile<<<fcGrid, blk, 0, stream>>>(xb, wall + 3 * WELEM, fc1_b, h1);
    ln_kernel<<<lnGrid, blk, 0, stream>>>(h1, xb, ln2_w, ln2_b, 1, 1);
    gemm_tile<<<fcGrid, blk, 0, stream>>>(xb, wall + 4 * WELEM, fc2_b, h2);
    ln_kernel<<<lnGrid, blk, 0, stream>>>(h2, out, norm_w, norm_b, 0, 0);
}